// Round 3
// baseline (202.926 us; speedup 1.0000x reference)
//
#include <hip/hip_runtime.h>

// B=2, S=2048, H=1024, NH=16, HD=64
// Reference reshape [B,S,H]->[B,NH,S,HD] is a VIEW: head n = flat chunk
// [n*S*HD, (n+1)*S*HD) per batch, i.e. a [2048,64] row-major block.
// out[b,q,n*64+d] = softmax_k(Q_n[q,:]·K_n[k,:]/8) @ V_n[k,d]

typedef short s16x8 __attribute__((ext_vector_type(8)));
typedef float f32x4 __attribute__((ext_vector_type(4)));

#define MFMA16(a, b, c) __builtin_amdgcn_mfma_f32_16x16x32_bf16((a), (b), (c), 0, 0, 0)

__device__ __forceinline__ short f2bf(float f) {
  // round-to-nearest-even fp32 -> bf16 (inputs are normal numbers)
  unsigned u = __builtin_bit_cast(unsigned, f);
  u = (u + 0x7fffu + ((u >> 16) & 1u)) >> 16;
  return (short)u;
}

struct ProjArgs {
  const float* X[3];
  const float* W[3];
  const float* Bv[3];
  short* Y[3];
  float scale[3];
};

// ---------------- Kernel 1: Y[z] = bf16((X[z] @ W[z]^T + b[z]) * scale[z])
// M=4096, N=1024, K=1024.  W is [N,K] row-major (torch Linear weight) -> B^T GEMM.
#define PBM 128
#define PBN 128
#define PBK 32
#define PLD (PBK + 8)  // padded leading dim in shorts (40)

__global__ __launch_bounds__(256) void qkv_proj_kernel(ProjArgs args) {
  const int z = blockIdx.z;
  const float* __restrict__ X = args.X[z];
  const float* __restrict__ W = args.W[z];
  const float* __restrict__ Bv = args.Bv[z];
  short* __restrict__ Y = args.Y[z];
  const float scale = args.scale[z];

  __shared__ __align__(16) short As[PBM][PLD];
  __shared__ __align__(16) short Bs[PBN][PLD];

  const int tid = threadIdx.x;
  const int lane = tid & 63;
  const int wave = tid >> 6;
  const int m0 = blockIdx.y * PBM;
  const int n0 = blockIdx.x * PBN;
  const int moff = (wave >> 1) * 64;
  const int noff = (wave & 1) * 64;
  const int fr = lane & 15;        // fragment row/col within 16
  const int fk = (lane >> 4) * 8;  // k offset within 32

  const int srow = tid >> 1;         // 0..127 staging row
  const int scol = (tid & 1) * 16;   // 0 or 16

  f32x4 acc[4][4] = {};

  const float* ap = X + (size_t)(m0 + srow) * 1024 + scol;
  const float* bp = W + (size_t)(n0 + srow) * 1024 + scol;

  for (int k0 = 0; k0 < 1024; k0 += PBK) {
    f32x4 a0 = *(const f32x4*)(ap + k0);
    f32x4 a1 = *(const f32x4*)(ap + k0 + 4);
    f32x4 a2 = *(const f32x4*)(ap + k0 + 8);
    f32x4 a3 = *(const f32x4*)(ap + k0 + 12);
    f32x4 b0 = *(const f32x4*)(bp + k0);
    f32x4 b1 = *(const f32x4*)(bp + k0 + 4);
    f32x4 b2 = *(const f32x4*)(bp + k0 + 8);
    f32x4 b3 = *(const f32x4*)(bp + k0 + 12);

    s16x8 sa0, sa1, sb0, sb1;
#pragma unroll
    for (int j = 0; j < 4; ++j) {
      sa0[j] = f2bf(a0[j]); sa0[j + 4] = f2bf(a1[j]);
      sa1[j] = f2bf(a2[j]); sa1[j + 4] = f2bf(a3[j]);
      sb0[j] = f2bf(b0[j]); sb0[j + 4] = f2bf(b1[j]);
      sb1[j] = f2bf(b2[j]); sb1[j + 4] = f2bf(b3[j]);
    }

    __syncthreads();  // previous-iter readers done before overwrite
    *(s16x8*)&As[srow][scol]     = sa0;
    *(s16x8*)&As[srow][scol + 8] = sa1;
    *(s16x8*)&Bs[srow][scol]     = sb0;
    *(s16x8*)&Bs[srow][scol + 8] = sb1;
    __syncthreads();

    s16x8 af[4], bfm[4];
#pragma unroll
    for (int i = 0; i < 4; ++i) af[i] = *(const s16x8*)&As[moff + i * 16 + fr][fk];
#pragma unroll
    for (int j = 0; j < 4; ++j) bfm[j] = *(const s16x8*)&Bs[noff + j * 16 + fr][fk];
#pragma unroll
    for (int i = 0; i < 4; ++i)
#pragma unroll
      for (int j = 0; j < 4; ++j)
        acc[i][j] = MFMA16(af[i], bfm[j], acc[i][j]);
  }

  // epilogue: C/D layout col = lane&15, row = (lane>>4)*4 + reg (m89-verified)
#pragma unroll
  for (int j = 0; j < 4; ++j) {
    const int col = n0 + noff + j * 16 + fr;
    const float bias = Bv[col];
#pragma unroll
    for (int i = 0; i < 4; ++i) {
      const int rowb = m0 + moff + i * 16 + (lane >> 4) * 4;
#pragma unroll
      for (int r = 0; r < 4; ++r) {
        Y[(size_t)(rowb + r) * 1024 + col] = f2bf((acc[i][j][r] + bias) * scale);
      }
    }
  }
}

// ---------------- Kernel 2: flash attention over 32 [2048,64] heads
#define QBLK 128
#define KVB 64
#define ALD 72  // 64 + 8 pad, shorts

__global__ __launch_bounds__(512) void attn_kernel(
    const short* __restrict__ Qb, const short* __restrict__ Kb,
    const short* __restrict__ Vb, float* __restrict__ out) {
  const int qb = blockIdx.x;    // 0..15 q tile
  const int head = blockIdx.y;  // 0..15
  const int bz = blockIdx.z;    // 0..1

  const size_t hb = (size_t)bz * (2048 * 1024) + (size_t)head * (2048 * 64);
  const short* Qh = Qb + hb;
  const short* Kh = Kb + hb;
  const short* Vh = Vb + hb;

  __shared__ __align__(16) short Qs[QBLK][ALD];
  __shared__ __align__(16) short Ks[KVB][ALD];
  __shared__ __align__(16) short Vts[64][ALD];   // V transposed: [d][k]
  __shared__ __align__(16) short Ps[QBLK][ALD];  // P, per-wave 16-row slabs

  const int tid = threadIdx.x;
  const int lane = tid & 63;
  const int wave = tid >> 6;  // 0..7, owns q rows [wave*16, wave*16+16)
  const int fr = lane & 15;
  const int fk = (lane >> 4) * 8;
  const int qlds = wave * 16;

  // stage Q tile [128][64]
  {
    const int r = tid >> 2;
    const int c = (tid & 3) * 16;
    const short* src = Qh + (size_t)(qb * QBLK + r) * 64 + c;
    *(s16x8*)&Qs[r][c]     = *(const s16x8*)src;
    *(s16x8*)&Qs[r][c + 8] = *(const s16x8*)(src + 8);
  }
  __syncthreads();

  // A-operand frags of Q are loop-invariant
  const s16x8 aq0 = *(const s16x8*)&Qs[qlds + fr][fk];
  const s16x8 aq1 = *(const s16x8*)&Qs[qlds + fr][32 + fk];

  float m_st[4], l_st[4];
  f32x4 acc[4] = {};  // O accumulator: [d-chunk][reg]
#pragma unroll
  for (int r = 0; r < 4; ++r) { m_st[r] = -1e30f; l_st[r] = 0.f; }

  const int sr = tid >> 3;       // 0..63 staging row
  const int sc = (tid & 7) * 8;  // 0..56

  for (int kv0 = 0; kv0 < 2048; kv0 += KVB) {
    // stage K [64][64] natural, V transposed
    s16x8 kvec = *(const s16x8*)(Kh + (size_t)(kv0 + sr) * 64 + sc);
    s16x8 vvec = *(const s16x8*)(Vh + (size_t)(kv0 + sr) * 64 + sc);
    *(s16x8*)&Ks[sr][sc] = kvec;
#pragma unroll
    for (int j = 0; j < 8; ++j) Vts[sc + j][sr] = vvec[j];
    __syncthreads();

    // E = (Q/8) K^T   (scale pre-folded into Q)
    f32x4 e[4];
#pragma unroll
    for (int f = 0; f < 4; ++f) {
      s16x8 bk0 = *(const s16x8*)&Ks[f * 16 + fr][fk];
      s16x8 bk1 = *(const s16x8*)&Ks[f * 16 + fr][32 + fk];
      f32x4 zz = {};
      zz = MFMA16(aq0, bk0, zz);
      e[f] = MFMA16(aq1, bk1, zz);
    }

    // online softmax; E row = (lane>>4)*4 + r, col = f*16 + fr
#pragma unroll
    for (int r = 0; r < 4; ++r) {
      float t = fmaxf(fmaxf(e[0][r], e[1][r]), fmaxf(e[2][r], e[3][r]));
#pragma unroll
      for (int off = 8; off >= 1; off >>= 1) t = fmaxf(t, __shfl_xor(t, off));
      const float mnew = fmaxf(m_st[r], t);
      const float corr = __expf(m_st[r] - mnew);
      m_st[r] = mnew;
      const float p0 = __expf(e[0][r] - mnew);
      const float p1 = __expf(e[1][r] - mnew);
      const float p2 = __expf(e[2][r] - mnew);
      const float p3 = __expf(e[3][r] - mnew);
      float s = (p0 + p1) + (p2 + p3);
#pragma unroll
      for (int off = 8; off >= 1; off >>= 1) s += __shfl_xor(s, off);
      l_st[r] = l_st[r] * corr + s;
#pragma unroll
      for (int d = 0; d < 4; ++d) acc[d][r] *= corr;
      const int prow = qlds + (lane >> 4) * 4 + r;
      Ps[prow][fr]      = f2bf(p0);
      Ps[prow][16 + fr] = f2bf(p1);
      Ps[prow][32 + fr] = f2bf(p2);
      Ps[prow][48 + fr] = f2bf(p3);
    }

    // O += P @ V  (P via per-wave LDS round-trip; V^T gives contiguous B frags)
    s16x8 pa0 = *(const s16x8*)&Ps[qlds + fr][fk];
    s16x8 pa1 = *(const s16x8*)&Ps[qlds + fr][32 + fk];
#pragma unroll
    for (int d = 0; d < 4; ++d) {
      s16x8 bv0 = *(const s16x8*)&Vts[d * 16 + fr][fk];
      s16x8 bv1 = *(const s16x8*)&Vts[d * 16 + fr][32 + fk];
      acc[d] = MFMA16(pa1, bv1, MFMA16(pa0, bv0, acc[d]));
    }
    __syncthreads();  // protect K/V/LDS restage
  }

  // epilogue: out[b, q, head*64 + d]
#pragma unroll
  for (int r = 0; r < 4; ++r) {
    const float inv = 1.0f / l_st[r];
    const int q = qb * QBLK + qlds + (lane >> 4) * 4 + r;
    float* op = out + ((size_t)bz * 2048 + q) * 1024 + head * 64;
#pragma unroll
    for (int d = 0; d < 4; ++d) op[d * 16 + fr] = acc[d][r] * inv;
  }
}

extern "C" void kernel_launch(void* const* d_in, const int* in_sizes, int n_in,
                              void* d_out, int out_size, void* d_ws, size_t ws_size,
                              hipStream_t stream) {
  const float* query = (const float*)d_in[0];
  const float* key   = (const float*)d_in[1];
  const float* value = (const float*)d_in[2];
  const float* Wq = (const float*)d_in[3];
  const float* bq = (const float*)d_in[4];
  const float* Wk = (const float*)d_in[5];
  const float* bk = (const float*)d_in[6];
  const float* Wv = (const float*)d_in[7];
  const float* bv = (const float*)d_in[8];
  float* out = (float*)d_out;

  short* Qw = (short*)d_ws;                       // [4096][1024] bf16, pre-scaled by 1/8
  short* Kw = Qw + (size_t)4096 * 1024;
  short* Vw = Kw + (size_t)4096 * 1024;

  ProjArgs pa;
  pa.X[0] = query; pa.X[1] = key; pa.X[2] = value;
  pa.W[0] = Wq; pa.W[1] = Wk; pa.W[2] = Wv;
  pa.Bv[0] = bq; pa.Bv[1] = bk; pa.Bv[2] = bv;
  pa.Y[0] = Qw; pa.Y[1] = Kw; pa.Y[2] = Vw;
  pa.scale[0] = 0.125f; pa.scale[1] = 1.0f; pa.scale[2] = 1.0f;

  qkv_proj_kernel<<<dim3(1024 / PBN, 4096 / PBM, 3), 256, 0, stream>>>(pa);
  attn_kernel<<<dim3(2048 / QBLK, 16, 2), 512, 0, stream>>>(Qw, Kw, Vw, out);
}

// Round 5
// 133.001 us; speedup vs baseline: 1.5258x; 1.5258x over previous
//
#include <hip/hip_runtime.h>

// B=2, S=2048, H=1024, NH=16, HD=64
// Reference reshape [B,S,H]->[B,NH,S,HD] is a VIEW: head n = flat chunk
// [n*S*HD, (n+1)*S*HD) per batch, i.e. a [2048,64] row-major block.
// out[b,q,n*64+d] = softmax_k(Q_n[q,:]·K_n[k,:]/8) @ V_n[k,d]

typedef short s16x8 __attribute__((ext_vector_type(8)));
typedef float f32x4 __attribute__((ext_vector_type(4)));
typedef float f32x16 __attribute__((ext_vector_type(16)));
typedef unsigned int u32x2 __attribute__((ext_vector_type(2)));
typedef unsigned int u32x4 __attribute__((ext_vector_type(4)));
typedef float f32x4u __attribute__((ext_vector_type(4), aligned(4)));

#define MFMA16(a, b, c) __builtin_amdgcn_mfma_f32_16x16x32_bf16((a), (b), (c), 0, 0, 0)
#define MFMA32(a, b, c) __builtin_amdgcn_mfma_f32_32x32x16_bf16((a), (b), (c), 0, 0, 0)

__device__ __forceinline__ short f2bf(float f) {
  unsigned u = __builtin_bit_cast(unsigned, f);
  u = (u + 0x7fffu + ((u >> 16) & 1u)) >> 16;
  return (short)u;
}

struct ProjArgs {
  const float* X[3];
  const float* W[3];
  const float* Bv[3];
  short* Y[3];
  float scale[3];
};

// ---------------- Kernel 1: Y[z] = bf16((X[z] @ W[z]^T + b[z]) * scale[z])
#define PBM 128
#define PBN 128
#define PBK 32
#define PLD (PBK + 8)

__global__ __launch_bounds__(256) void qkv_proj_kernel(ProjArgs args) {
  const int z = blockIdx.z;
  const float* __restrict__ X = args.X[z];
  const float* __restrict__ W = args.W[z];
  const float* __restrict__ Bv = args.Bv[z];
  short* __restrict__ Y = args.Y[z];
  const float scale = args.scale[z];

  __shared__ __align__(16) short As[PBM][PLD];
  __shared__ __align__(16) short Bs[PBN][PLD];

  const int tid = threadIdx.x;
  const int lane = tid & 63;
  const int wave = tid >> 6;
  const int m0 = blockIdx.y * PBM;
  const int n0 = blockIdx.x * PBN;
  const int moff = (wave >> 1) * 64;
  const int noff = (wave & 1) * 64;
  const int fr = lane & 15;
  const int fk = (lane >> 4) * 8;

  const int srow = tid >> 1;
  const int scol = (tid & 1) * 16;

  f32x4 acc[4][4] = {};

  const float* ap = X + (size_t)(m0 + srow) * 1024 + scol;
  const float* bp = W + (size_t)(n0 + srow) * 1024 + scol;

  for (int k0 = 0; k0 < 1024; k0 += PBK) {
    f32x4 a0 = *(const f32x4*)(ap + k0);
    f32x4 a1 = *(const f32x4*)(ap + k0 + 4);
    f32x4 a2 = *(const f32x4*)(ap + k0 + 8);
    f32x4 a3 = *(const f32x4*)(ap + k0 + 12);
    f32x4 b0 = *(const f32x4*)(bp + k0);
    f32x4 b1 = *(const f32x4*)(bp + k0 + 4);
    f32x4 b2 = *(const f32x4*)(bp + k0 + 8);
    f32x4 b3 = *(const f32x4*)(bp + k0 + 12);

    s16x8 sa0, sa1, sb0, sb1;
#pragma unroll
    for (int j = 0; j < 4; ++j) {
      sa0[j] = f2bf(a0[j]); sa0[j + 4] = f2bf(a1[j]);
      sa1[j] = f2bf(a2[j]); sa1[j + 4] = f2bf(a3[j]);
      sb0[j] = f2bf(b0[j]); sb0[j + 4] = f2bf(b1[j]);
      sb1[j] = f2bf(b2[j]); sb1[j + 4] = f2bf(b3[j]);
    }

    __syncthreads();
    *(s16x8*)&As[srow][scol]     = sa0;
    *(s16x8*)&As[srow][scol + 8] = sa1;
    *(s16x8*)&Bs[srow][scol]     = sb0;
    *(s16x8*)&Bs[srow][scol + 8] = sb1;
    __syncthreads();

    s16x8 af[4], bfm[4];
#pragma unroll
    for (int i = 0; i < 4; ++i) af[i] = *(const s16x8*)&As[moff + i * 16 + fr][fk];
#pragma unroll
    for (int j = 0; j < 4; ++j) bfm[j] = *(const s16x8*)&Bs[noff + j * 16 + fr][fk];
#pragma unroll
    for (int i = 0; i < 4; ++i)
#pragma unroll
      for (int j = 0; j < 4; ++j)
        acc[i][j] = MFMA16(af[i], bfm[j], acc[i][j]);
  }

#pragma unroll
  for (int j = 0; j < 4; ++j) {
    const int col = n0 + noff + j * 16 + fr;
    const float bias = Bv[col];
#pragma unroll
    for (int i = 0; i < 4; ++i) {
      const int rowb = m0 + moff + i * 16 + (lane >> 4) * 4;
#pragma unroll
      for (int r = 0; r < 4; ++r) {
        Y[(size_t)(rowb + r) * 1024 + col] = f2bf((acc[i][j][r] + bias) * scale);
      }
    }
  }
}

// ---------------- Kernel 2: flash attention, swapped-operand 32x32 MFMA.
// 256 thr (4 waves), wave owns 32 q-rows; QBLK=128; KVB=64.
// E^T = K·Q^T (lane owns q = lane&31); P^T exchanged hi<->hi+32 via
// __shfl_xor(32)+select; O^T = V^T·P, V^T via ds_read_b64_tr_b16 with
// PER-LANE addresses base+(l&15)*8 into subtiled LDS; K XOR-swizzled LDS.

#define TRR(dst, base, OFF) \
  asm volatile("ds_read_b64_tr_b16 %0, %1 offset:" OFF : "=v"(dst) : "v"(base))

__global__ __launch_bounds__(256, 2) void attn_kernel(
    const short* __restrict__ Qb, const short* __restrict__ Kb,
    const short* __restrict__ Vb, float* __restrict__ out) {
  const int head = blockIdx.x;  // 0..15
  const int bz = blockIdx.y;    // 0..1
  const int qb = blockIdx.z;    // 0..15

  const size_t hb = (size_t)bz * (2048 * 1024) + (size_t)head * (2048 * 64);
  const short* __restrict__ Qh = Qb + hb;
  const short* __restrict__ Kh = Kb + hb;
  const short* __restrict__ Vh = Vb + hb;

  // K: [64 rows][128B], byte ^= ((row&7)<<4).
  // V: subtiled [k>>2][d>>4][k&3][d&15] (64-elem = 128B subtiles) for tr_b16.
  __shared__ __align__(16) short Klds[2][4096];
  __shared__ __align__(16) short Vlds[2][4096];

  const int tid = threadIdx.x;
  const int lane = tid & 63;
  const int wave = tid >> 6;
  const int l31 = lane & 31;
  const int hi = lane >> 5;

  // ---- Q B-operand frags (loop-invariant): B[kk=d][j=q] = Q[q][f*16+hi*8+i]
  const int q0w = qb * 128 + wave * 32;
  s16x8 qf[4];
#pragma unroll
  for (int f = 0; f < 4; ++f)
    qf[f] = *(const s16x8*)(Qh + (size_t)(q0w + l31) * 64 + f * 16 + hi * 8);

  // ---- staging mapping (256 threads stage 64x64 K and V tiles)
  const int kr = tid >> 2;        // 0..63 row
  const int kc = (tid & 3) * 16;  // K col elems
  const int ksw = (kr & 7) << 4;
  const int kb0 = kr * 128 + ((kc * 2) ^ ksw);
  const int kb1 = kr * 128 + ((kc * 2 + 16) ^ ksw);
  const int vd0 = (tid & 3) * 16 + (((tid >> 4) & 1) * 8);
  const int vd1 = vd0 ^ 8;
  const int vb0w = ((kr >> 2) * 4 + (vd0 >> 4)) * 128 + (kr & 3) * 32 + (vd0 & 15) * 2;
  const int vb1w = ((kr >> 2) * 4 + (vd1 >> 4)) * 128 + (kr & 3) * 32 + (vd1 & 15) * 2;

  // K-frag read col-xor consts (read mirrors write swizzle)
  int cXor[4];
#pragma unroll
  for (int f = 0; f < 4; ++f) cXor[f] = ((f * 32 + hi * 16) ^ ((l31 & 7) << 4));

  // V tr_read per-lane byte offset: subtile (kt,dt) at (kt*4+dt)*128;
  // kt = k0i*4 + hi*2 + h, dt = dtB*2 + (l31>>4); lane supplies +(l&15)*8.
  const unsigned vlane = (unsigned)(hi * 1024 + ((l31 >> 4) * 128) + (lane & 15) * 8);

  // ---- prologue: stage tile 0
  s16x8 kn0 = *(const s16x8*)(Kh + kr * 64 + kc);
  s16x8 kn1 = *(const s16x8*)(Kh + kr * 64 + kc + 8);
  s16x8 vn0 = *(const s16x8*)(Vh + kr * 64 + vd0);
  s16x8 vn1 = *(const s16x8*)(Vh + kr * 64 + vd1);
  *(s16x8*)((char*)&Klds[0][0] + kb0) = kn0;
  *(s16x8*)((char*)&Klds[0][0] + kb1) = kn1;
  *(s16x8*)((char*)&Vlds[0][0] + vb0w) = vn0;
  *(s16x8*)((char*)&Vlds[0][0] + vb1w) = vn1;

  float m = -1e30f, lsum = 0.f;
  f32x16 acc0 = {}, acc1 = {};

  for (int t = 0; t < 32; ++t) {
    __syncthreads();
    const int cur = t & 1;

    if (t < 31) {  // prefetch next tile global->reg (lands under compute)
      const short* kg = Kh + (size_t)(t + 1) * 4096 + kr * 64 + kc;
      kn0 = *(const s16x8*)kg;
      kn1 = *(const s16x8*)(kg + 8);
      const short* vg = Vh + (size_t)(t + 1) * 4096 + kr * 64;
      vn0 = *(const s16x8*)(vg + vd0);
      vn1 = *(const s16x8*)(vg + vd1);
    }

    // ---- QK: E^T[k][q]; A = K (row k = l&31), B = Q (col q = l&31)
    const char* kl = (const char*)&Klds[cur][0];
    f32x16 et0 = {}, et1 = {};
#pragma unroll
    for (int f = 0; f < 4; ++f) {
      s16x8 kf = *(const s16x8*)(kl + l31 * 128 + cXor[f]);
      et0 = MFMA32(kf, qf[f], et0);
    }
#pragma unroll
    for (int f = 0; f < 4; ++f) {
      s16x8 kf = *(const s16x8*)(kl + 4096 + l31 * 128 + cXor[f]);
      et1 = MFMA32(kf, qf[f], et1);
    }

    // ---- online softmax (lane owns one q; halves merge via shfl_xor 32)
    float mx[16];
#pragma unroll
    for (int r = 0; r < 16; ++r) mx[r] = fmaxf(et0[r], et1[r]);
#pragma unroll
    for (int s2 = 8; s2 >= 1; s2 >>= 1)
#pragma unroll
      for (int r = 0; r < 8; ++r)
        if (r < s2) mx[r] = fmaxf(mx[r], mx[r + s2]);
    float mt = fmaxf(mx[0], __shfl_xor(mx[0], 32));
    const float mnew = fmaxf(m, mt);
    const float corr = __expf(m - mnew);
    m = mnew;

    float p0a[16], p1a[16], sm[16];
#pragma unroll
    for (int r = 0; r < 16; ++r) {
      p0a[r] = __expf(et0[r] - mnew);
      p1a[r] = __expf(et1[r] - mnew);
      sm[r] = p0a[r] + p1a[r];
    }
#pragma unroll
    for (int s2 = 8; s2 >= 1; s2 >>= 1)
#pragma unroll
      for (int r = 0; r < 8; ++r)
        if (r < s2) sm[r] += sm[r + s2];
    const float stot = sm[0] + __shfl_xor(sm[0], 32);
    lsum = lsum * corr + stot;
    acc0 *= corr;
    acc1 *= corr;

    // ---- pack P^T -> bf16 pairs. Reg r of tile T: k = 32T + 8(r>>2)+(r&3)+4hi.
    // xr[T][c] = k pair {8c+4hi+0,1}+32T ; yr[T][c] = {8c+4hi+2,3}+32T.
    unsigned xr[2][4], yr[2][4];
#pragma unroll
    for (int c = 0; c < 4; ++c) {
      asm("v_cvt_pk_bf16_f32 %0, %1, %2" : "=v"(xr[0][c]) : "v"(p0a[4 * c + 0]), "v"(p0a[4 * c + 1]));
      asm("v_cvt_pk_bf16_f32 %0, %1, %2" : "=v"(yr[0][c]) : "v"(p0a[4 * c + 2]), "v"(p0a[4 * c + 3]));
      asm("v_cvt_pk_bf16_f32 %0, %1, %2" : "=v"(xr[1][c]) : "v"(p1a[4 * c + 0]), "v"(p1a[4 * c + 1]));
      asm("v_cvt_pk_bf16_f32 %0, %1, %2" : "=v"(yr[1][c]) : "v"(p1a[4 * c + 2]), "v"(p1a[4 * c + 3]));
    }
    // B-frag pf[2T+u] word w must hold k = 32T + 16u + 8hi + 2w + {0,1}.
    // hi=0 needs: w0=own xr[2u], w1=own yr[2u], w2=partner xr[2u], w3=partner yr[2u]
    // hi=1 needs: w0=partner xr[2u+1], w1=partner yr[2u+1], w2=own xr[2u+1], w3=own yr[2u+1]
    s16x8 pf[4];
#pragma unroll
    for (int T = 0; T < 2; ++T)
#pragma unroll
      for (int u = 0; u < 2; ++u) {
        unsigned kx = hi ? xr[T][2 * u + 1] : xr[T][2 * u];      // kept
        unsigned sx = hi ? xr[T][2 * u]     : xr[T][2 * u + 1];  // sent
        unsigned ky = hi ? yr[T][2 * u + 1] : yr[T][2 * u];
        unsigned sy = hi ? yr[T][2 * u]     : yr[T][2 * u + 1];
        unsigned rx = (unsigned)__shfl_xor((int)sx, 32);
        unsigned ry = (unsigned)__shfl_xor((int)sy, 32);
        u32x4 w = {hi ? rx : kx, hi ? ry : ky, hi ? kx : rx, hi ? ky : ry};
        pf[2 * T + u] = __builtin_bit_cast(s16x8, w);
      }

    // ---- PV: O^T += V^T · P ; V^T A-frags via tr_b16, per-lane addressed
    const unsigned vb = (unsigned)(size_t)((const char*)&Vlds[cur][0]) + vlane;
    u32x2 va[2][4][2];  // [dtB][k0i][h]
    TRR(va[0][0][0], vb, "0");    TRR(va[0][0][1], vb, "512");
    TRR(va[0][1][0], vb, "2048"); TRR(va[0][1][1], vb, "2560");
    TRR(va[0][2][0], vb, "4096"); TRR(va[0][2][1], vb, "4608");
    TRR(va[0][3][0], vb, "6144"); TRR(va[0][3][1], vb, "6656");
    TRR(va[1][0][0], vb, "256");  TRR(va[1][0][1], vb, "768");
    TRR(va[1][1][0], vb, "2304"); TRR(va[1][1][1], vb, "2816");
    TRR(va[1][2][0], vb, "4352"); TRR(va[1][2][1], vb, "4864");
    TRR(va[1][3][0], vb, "6400"); TRR(va[1][3][1], vb, "6912");
    asm volatile("s_waitcnt lgkmcnt(0)" ::: "memory");
    __builtin_amdgcn_sched_barrier(0);
#pragma unroll
    for (int k0i = 0; k0i < 4; ++k0i) {
      u32x4 w0 = {va[0][k0i][0][0], va[0][k0i][0][1], va[0][k0i][1][0], va[0][k0i][1][1]};
      u32x4 w1 = {va[1][k0i][0][0], va[1][k0i][0][1], va[1][k0i][1][0], va[1][k0i][1][1]};
      acc0 = MFMA32(__builtin_bit_cast(s16x8, w0), pf[k0i], acc0);
      acc1 = MFMA32(__builtin_bit_cast(s16x8, w1), pf[k0i], acc1);
    }

    if (t < 31) {  // stage next tile reg->LDS (other buffer)
      char* kld = (char*)&Klds[cur ^ 1][0];
      char* vld = (char*)&Vlds[cur ^ 1][0];
      *(s16x8*)(kld + kb0) = kn0;
      *(s16x8*)(kld + kb1) = kn1;
      *(s16x8*)(vld + vb0w) = vn0;
      *(s16x8*)(vld + vb1w) = vn1;
    }
  }

  // ---- epilogue: O^T col q = lane&31, row d = (r&3)+8*(r>>2)+4*hi (+32 for acc1)
  const float inv = 1.0f / lsum;
  acc0 *= inv;
  acc1 *= inv;
  float* op = out + ((size_t)bz * 2048 + q0w + l31) * 1024 + head * 64;
#pragma unroll
  for (int c = 0; c < 4; ++c) {
    f32x4u v0 = {acc0[4 * c + 0], acc0[4 * c + 1], acc0[4 * c + 2], acc0[4 * c + 3]};
    f32x4u v1 = {acc1[4 * c + 0], acc1[4 * c + 1], acc1[4 * c + 2], acc1[4 * c + 3]};
    *(f32x4u*)(op + 8 * c + 4 * hi) = v0;
    *(f32x4u*)(op + 32 + 8 * c + 4 * hi) = v1;
  }
}

extern "C" void kernel_launch(void* const* d_in, const int* in_sizes, int n_in,
                              void* d_out, int out_size, void* d_ws, size_t ws_size,
                              hipStream_t stream) {
  const float* query = (const float*)d_in[0];
  const float* key   = (const float*)d_in[1];
  const float* value = (const float*)d_in[2];
  const float* Wq = (const float*)d_in[3];
  const float* bq = (const float*)d_in[4];
  const float* Wk = (const float*)d_in[5];
  const float* bk = (const float*)d_in[6];
  const float* Wv = (const float*)d_in[7];
  const float* bv = (const float*)d_in[8];
  float* out = (float*)d_out;

  short* Qw = (short*)d_ws;  // [4096][1024] bf16, Q pre-scaled by 1/8
  short* Kw = Qw + (size_t)4096 * 1024;
  short* Vw = Kw + (size_t)4096 * 1024;

  ProjArgs pa;
  pa.X[0] = query; pa.X[1] = key; pa.X[2] = value;
  pa.W[0] = Wq; pa.W[1] = Wk; pa.W[2] = Wv;
  pa.Bv[0] = bq; pa.Bv[1] = bk; pa.Bv[2] = bv;
  pa.Y[0] = Qw; pa.Y[1] = Kw; pa.Y[2] = Vw;
  pa.scale[0] = 0.125f; pa.scale[1] = 1.0f; pa.scale[2] = 1.0f;

  qkv_proj_kernel<<<dim3(1024 / PBN, 4096 / PBM, 3), 256, 0, stream>>>(pa);
  attn_kernel<<<dim3(16, 2, 16), 256, 0, stream>>>(Qw, Kw, Vw, out);
}

// Round 6
// 128.717 us; speedup vs baseline: 1.5765x; 1.0333x over previous
//
#include <hip/hip_runtime.h>

// B=2, S=2048, H=1024, NH=16, HD=64
// Reference reshape [B,S,H]->[B,NH,S,HD] is a VIEW: head n = flat chunk
// [n*S*HD, (n+1)*S*HD) per batch, i.e. a [2048,64] row-major block.
// out[b,q,n*64+d] = softmax_k(Q_n[q,:]·K_n[k,:]/8) @ V_n[k,d]

typedef short s16x8 __attribute__((ext_vector_type(8)));
typedef float f32x4 __attribute__((ext_vector_type(4)));
typedef float f32x16 __attribute__((ext_vector_type(16)));
typedef unsigned int u32x2 __attribute__((ext_vector_type(2)));
typedef unsigned int u32x4 __attribute__((ext_vector_type(4)));
typedef float f32x4u __attribute__((ext_vector_type(4), aligned(4)));

#define MFMA16(a, b, c) __builtin_amdgcn_mfma_f32_16x16x32_bf16((a), (b), (c), 0, 0, 0)
#define MFMA32(a, b, c) __builtin_amdgcn_mfma_f32_32x32x16_bf16((a), (b), (c), 0, 0, 0)

__device__ __forceinline__ short f2bf(float f) {
  unsigned u = __builtin_bit_cast(unsigned, f);
  u = (u + 0x7fffu + ((u >> 16) & 1u)) >> 16;
  return (short)u;
}

// ================= Kernel 0: fp32 -> bf16 convert (X[3] then W[3]) =========
// X arrays: 3 x 4096*1024 (2^22 each); W arrays: 3 x 1024*1024 (2^20 each).
struct CvtArgs {
  const float* X[3];
  const float* W[3];
  short* Xb;  // [3][4096][1024]
  short* Wb;  // [3][1024][1024]
};

__global__ __launch_bounds__(256) void cvt_kernel(CvtArgs a) {
  const size_t t = (size_t)blockIdx.x * 256 + threadIdx.x;
  const size_t e = t * 8;
  const float* src;
  short* dst;
  size_t off;
  if (e < (size_t)3 * 4194304) {
    src = a.X[e >> 22];
    off = e & 4194303;
    dst = a.Xb + e;
  } else {
    const size_t e2 = e - (size_t)3 * 4194304;
    src = a.W[e2 >> 20];
    off = e2 & 1048575;
    dst = a.Wb + e2;
  }
  f32x4 v0 = *(const f32x4*)(src + off);
  f32x4 v1 = *(const f32x4*)(src + off + 4);
  s16x8 o;
#pragma unroll
  for (int j = 0; j < 4; ++j) { o[j] = f2bf(v0[j]); o[j + 4] = f2bf(v1[j]); }
  *(s16x8*)dst = o;
}

// ================= Kernel 1b: bf16 GEMM, m97 structure =====================
// Y[z] = bf16((Xb[z] @ Wb[z]^T + b[z]) * scale[z]); 128x128 tile, BK=64,
// global_load_lds width-16 staging, linear LDS, XCD-chunked 1D grid swizzle.
struct Gemm2Args {
  const short* Xb;
  const short* Wb;
  const float* Bv[3];
  short* Y[3];
  float scale[3];
};

__global__ __launch_bounds__(256) void qkv_gemm_bf16(Gemm2Args a) {
  // T1 swizzle: nwg=768, cpx=96 -> consecutive logical ids share an XCD L2.
  const int L = (blockIdx.x & 7) * 96 + (blockIdx.x >> 3);
  const int n_t = L & 7;
  const int m_t = (L >> 3) & 31;
  const int z = L >> 8;

  const short* __restrict__ Xz = a.Xb + (size_t)z * 4096 * 1024;
  const short* __restrict__ Wz = a.Wb + (size_t)z * 1024 * 1024;
  const float* __restrict__ Bv = a.Bv[z];
  short* __restrict__ Y = a.Y[z];
  const float scale = a.scale[z];

  __shared__ __align__(16) short As[128 * 64];
  __shared__ __align__(16) short Bs[128 * 64];

  const int tid = threadIdx.x;
  const int lane = tid & 63;
  const int wave = tid >> 6;
  const int m0 = m_t * 128;
  const int n0 = n_t * 128;
  const int moff = (wave >> 1) * 64;
  const int noff = (wave & 1) * 64;
  const int fr = lane & 15;
  const int fk = (lane >> 4) * 8;

  // staging: chunk c = wave*4+i covers rows [c*8, c*8+8); lane -> row c*8+(l>>3),
  // 16B col (l&7). LDS dest = base + c*1024B (wave-uniform), lane offset is HW.
  const int srow = lane >> 3;
  const int scol = (lane & 7) * 8;

  f32x4 acc[4][4] = {};

  for (int k0 = 0; k0 < 1024; k0 += 64) {
    __syncthreads();  // previous-iter readers done
#pragma unroll
    for (int i = 0; i < 4; ++i) {
      const int c = wave * 4 + i;
      const short* ga = Xz + (size_t)(m0 + c * 8 + srow) * 1024 + k0 + scol;
      const short* gb = Wz + (size_t)(n0 + c * 8 + srow) * 1024 + k0 + scol;
      __builtin_amdgcn_global_load_lds(
          (const __attribute__((address_space(1))) unsigned int*)ga,
          (__attribute__((address_space(3))) unsigned int*)&As[c * 512], 16, 0, 0);
      __builtin_amdgcn_global_load_lds(
          (const __attribute__((address_space(1))) unsigned int*)gb,
          (__attribute__((address_space(3))) unsigned int*)&Bs[c * 512], 16, 0, 0);
    }
    __syncthreads();  // compiler drains vmcnt before barrier

#pragma unroll
    for (int kk = 0; kk < 64; kk += 32) {
      s16x8 af[4], bf[4];
#pragma unroll
      for (int i = 0; i < 4; ++i) af[i] = *(const s16x8*)&As[(moff + i * 16 + fr) * 64 + kk + fk];
#pragma unroll
      for (int j = 0; j < 4; ++j) bf[j] = *(const s16x8*)&Bs[(noff + j * 16 + fr) * 64 + kk + fk];
#pragma unroll
      for (int i = 0; i < 4; ++i)
#pragma unroll
        for (int j = 0; j < 4; ++j)
          acc[i][j] = MFMA16(af[i], bf[j], acc[i][j]);
    }
  }

  // epilogue: C col = n-idx (lane&15), row = (lane>>4)*4 + reg
#pragma unroll
  for (int j = 0; j < 4; ++j) {
    const int col = n0 + noff + j * 16 + fr;
    const float bias = Bv[col];
#pragma unroll
    for (int i = 0; i < 4; ++i) {
      const int rowb = m0 + moff + i * 16 + (lane >> 4) * 4;
#pragma unroll
      for (int r = 0; r < 4; ++r) {
        Y[(size_t)(rowb + r) * 1024 + col] = f2bf((acc[i][j][r] + bias) * scale);
      }
    }
  }
}

// ================= Kernel 1 (fallback, fp32 inputs): R5 proj ===============
struct ProjArgs {
  const float* X[3];
  const float* W[3];
  const float* Bv[3];
  short* Y[3];
  float scale[3];
};

#define PBM 128
#define PBN 128
#define PBK 32
#define PLD (PBK + 8)

__global__ __launch_bounds__(256) void qkv_proj_fallback(ProjArgs args) {
  const int z = blockIdx.z;
  const float* __restrict__ X = args.X[z];
  const float* __restrict__ W = args.W[z];
  const float* __restrict__ Bv = args.Bv[z];
  short* __restrict__ Y = args.Y[z];
  const float scale = args.scale[z];

  __shared__ __align__(16) short As[PBM][PLD];
  __shared__ __align__(16) short Bs[PBN][PLD];

  const int tid = threadIdx.x;
  const int lane = tid & 63;
  const int wave = tid >> 6;
  const int m0 = blockIdx.y * PBM;
  const int n0 = blockIdx.x * PBN;
  const int moff = (wave >> 1) * 64;
  const int noff = (wave & 1) * 64;
  const int fr = lane & 15;
  const int fk = (lane >> 4) * 8;

  const int srow = tid >> 1;
  const int scol = (tid & 1) * 16;

  f32x4 acc[4][4] = {};

  const float* ap = X + (size_t)(m0 + srow) * 1024 + scol;
  const float* bp = W + (size_t)(n0 + srow) * 1024 + scol;

  for (int k0 = 0; k0 < 1024; k0 += PBK) {
    f32x4 a0 = *(const f32x4*)(ap + k0);
    f32x4 a1 = *(const f32x4*)(ap + k0 + 4);
    f32x4 a2 = *(const f32x4*)(ap + k0 + 8);
    f32x4 a3 = *(const f32x4*)(ap + k0 + 12);
    f32x4 b0 = *(const f32x4*)(bp + k0);
    f32x4 b1 = *(const f32x4*)(bp + k0 + 4);
    f32x4 b2 = *(const f32x4*)(bp + k0 + 8);
    f32x4 b3 = *(const f32x4*)(bp + k0 + 12);

    s16x8 sa0, sa1, sb0, sb1;
#pragma unroll
    for (int j = 0; j < 4; ++j) {
      sa0[j] = f2bf(a0[j]); sa0[j + 4] = f2bf(a1[j]);
      sa1[j] = f2bf(a2[j]); sa1[j + 4] = f2bf(a3[j]);
      sb0[j] = f2bf(b0[j]); sb0[j + 4] = f2bf(b1[j]);
      sb1[j] = f2bf(b2[j]); sb1[j + 4] = f2bf(b3[j]);
    }

    __syncthreads();
    *(s16x8*)&As[srow][scol]     = sa0;
    *(s16x8*)&As[srow][scol + 8] = sa1;
    *(s16x8*)&Bs[srow][scol]     = sb0;
    *(s16x8*)&Bs[srow][scol + 8] = sb1;
    __syncthreads();

    s16x8 af[4], bfm[4];
#pragma unroll
    for (int i = 0; i < 4; ++i) af[i] = *(const s16x8*)&As[moff + i * 16 + fr][fk];
#pragma unroll
    for (int j = 0; j < 4; ++j) bfm[j] = *(const s16x8*)&Bs[noff + j * 16 + fr][fk];
#pragma unroll
    for (int i = 0; i < 4; ++i)
#pragma unroll
      for (int j = 0; j < 4; ++j)
        acc[i][j] = MFMA16(af[i], bfm[j], acc[i][j]);
  }

#pragma unroll
  for (int j = 0; j < 4; ++j) {
    const int col = n0 + noff + j * 16 + fr;
    const float bias = Bv[col];
#pragma unroll
    for (int i = 0; i < 4; ++i) {
      const int rowb = m0 + moff + i * 16 + (lane >> 4) * 4;
#pragma unroll
      for (int r = 0; r < 4; ++r) {
        Y[(size_t)(rowb + r) * 1024 + col] = f2bf((acc[i][j][r] + bias) * scale);
      }
    }
  }
}

// ================= Kernel 2: flash attention (unchanged from R5) ===========
#define TRR(dst, base, OFF) \
  asm volatile("ds_read_b64_tr_b16 %0, %1 offset:" OFF : "=v"(dst) : "v"(base))

__global__ __launch_bounds__(256, 2) void attn_kernel(
    const short* __restrict__ Qb, const short* __restrict__ Kb,
    const short* __restrict__ Vb, float* __restrict__ out) {
  const int head = blockIdx.x;  // 0..15
  const int bz = blockIdx.y;    // 0..1
  const int qb = blockIdx.z;    // 0..15

  const size_t hb = (size_t)bz * (2048 * 1024) + (size_t)head * (2048 * 64);
  const short* __restrict__ Qh = Qb + hb;
  const short* __restrict__ Kh = Kb + hb;
  const short* __restrict__ Vh = Vb + hb;

  __shared__ __align__(16) short Klds[2][4096];
  __shared__ __align__(16) short Vlds[2][4096];

  const int tid = threadIdx.x;
  const int lane = tid & 63;
  const int wave = tid >> 6;
  const int l31 = lane & 31;
  const int hi = lane >> 5;

  const int q0w = qb * 128 + wave * 32;
  s16x8 qf[4];
#pragma unroll
  for (int f = 0; f < 4; ++f)
    qf[f] = *(const s16x8*)(Qh + (size_t)(q0w + l31) * 64 + f * 16 + hi * 8);

  const int kr = tid >> 2;
  const int kc = (tid & 3) * 16;
  const int ksw = (kr & 7) << 4;
  const int kb0 = kr * 128 + ((kc * 2) ^ ksw);
  const int kb1 = kr * 128 + ((kc * 2 + 16) ^ ksw);
  const int vd0 = (tid & 3) * 16 + (((tid >> 4) & 1) * 8);
  const int vd1 = vd0 ^ 8;
  const int vb0w = ((kr >> 2) * 4 + (vd0 >> 4)) * 128 + (kr & 3) * 32 + (vd0 & 15) * 2;
  const int vb1w = ((kr >> 2) * 4 + (vd1 >> 4)) * 128 + (kr & 3) * 32 + (vd1 & 15) * 2;

  int cXor[4];
#pragma unroll
  for (int f = 0; f < 4; ++f) cXor[f] = ((f * 32 + hi * 16) ^ ((l31 & 7) << 4));

  const unsigned vlane = (unsigned)(hi * 1024 + ((l31 >> 4) * 128) + (lane & 15) * 8);

  s16x8 kn0 = *(const s16x8*)(Kh + kr * 64 + kc);
  s16x8 kn1 = *(const s16x8*)(Kh + kr * 64 + kc + 8);
  s16x8 vn0 = *(const s16x8*)(Vh + kr * 64 + vd0);
  s16x8 vn1 = *(const s16x8*)(Vh + kr * 64 + vd1);
  *(s16x8*)((char*)&Klds[0][0] + kb0) = kn0;
  *(s16x8*)((char*)&Klds[0][0] + kb1) = kn1;
  *(s16x8*)((char*)&Vlds[0][0] + vb0w) = vn0;
  *(s16x8*)((char*)&Vlds[0][0] + vb1w) = vn1;

  float m = -1e30f, lsum = 0.f;
  f32x16 acc0 = {}, acc1 = {};

  for (int t = 0; t < 32; ++t) {
    __syncthreads();
    const int cur = t & 1;

    if (t < 31) {
      const short* kg = Kh + (size_t)(t + 1) * 4096 + kr * 64 + kc;
      kn0 = *(const s16x8*)kg;
      kn1 = *(const s16x8*)(kg + 8);
      const short* vg = Vh + (size_t)(t + 1) * 4096 + kr * 64;
      vn0 = *(const s16x8*)(vg + vd0);
      vn1 = *(const s16x8*)(vg + vd1);
    }

    const char* kl = (const char*)&Klds[cur][0];
    f32x16 et0 = {}, et1 = {};
#pragma unroll
    for (int f = 0; f < 4; ++f) {
      s16x8 kf = *(const s16x8*)(kl + l31 * 128 + cXor[f]);
      et0 = MFMA32(kf, qf[f], et0);
    }
#pragma unroll
    for (int f = 0; f < 4; ++f) {
      s16x8 kf = *(const s16x8*)(kl + 4096 + l31 * 128 + cXor[f]);
      et1 = MFMA32(kf, qf[f], et1);
    }

    float mx[16];
#pragma unroll
    for (int r = 0; r < 16; ++r) mx[r] = fmaxf(et0[r], et1[r]);
#pragma unroll
    for (int s2 = 8; s2 >= 1; s2 >>= 1)
#pragma unroll
      for (int r = 0; r < 8; ++r)
        if (r < s2) mx[r] = fmaxf(mx[r], mx[r + s2]);
    float mt = fmaxf(mx[0], __shfl_xor(mx[0], 32));
    const float mnew = fmaxf(m, mt);
    const float corr = __expf(m - mnew);
    m = mnew;

    float p0a[16], p1a[16], sm[16];
#pragma unroll
    for (int r = 0; r < 16; ++r) {
      p0a[r] = __expf(et0[r] - mnew);
      p1a[r] = __expf(et1[r] - mnew);
      sm[r] = p0a[r] + p1a[r];
    }
#pragma unroll
    for (int s2 = 8; s2 >= 1; s2 >>= 1)
#pragma unroll
      for (int r = 0; r < 8; ++r)
        if (r < s2) sm[r] += sm[r + s2];
    const float stot = sm[0] + __shfl_xor(sm[0], 32);
    lsum = lsum * corr + stot;
    acc0 *= corr;
    acc1 *= corr;

    unsigned xr[2][4], yr[2][4];
#pragma unroll
    for (int c = 0; c < 4; ++c) {
      asm("v_cvt_pk_bf16_f32 %0, %1, %2" : "=v"(xr[0][c]) : "v"(p0a[4 * c + 0]), "v"(p0a[4 * c + 1]));
      asm("v_cvt_pk_bf16_f32 %0, %1, %2" : "=v"(yr[0][c]) : "v"(p0a[4 * c + 2]), "v"(p0a[4 * c + 3]));
      asm("v_cvt_pk_bf16_f32 %0, %1, %2" : "=v"(xr[1][c]) : "v"(p1a[4 * c + 0]), "v"(p1a[4 * c + 1]));
      asm("v_cvt_pk_bf16_f32 %0, %1, %2" : "=v"(yr[1][c]) : "v"(p1a[4 * c + 2]), "v"(p1a[4 * c + 3]));
    }
    s16x8 pf[4];
#pragma unroll
    for (int T = 0; T < 2; ++T)
#pragma unroll
      for (int u = 0; u < 2; ++u) {
        unsigned kx = hi ? xr[T][2 * u + 1] : xr[T][2 * u];
        unsigned sx = hi ? xr[T][2 * u]     : xr[T][2 * u + 1];
        unsigned ky = hi ? yr[T][2 * u + 1] : yr[T][2 * u];
        unsigned sy = hi ? yr[T][2 * u]     : yr[T][2 * u + 1];
        unsigned rx = (unsigned)__shfl_xor((int)sx, 32);
        unsigned ry = (unsigned)__shfl_xor((int)sy, 32);
        u32x4 w = {hi ? rx : kx, hi ? ry : ky, hi ? kx : rx, hi ? ky : ry};
        pf[2 * T + u] = __builtin_bit_cast(s16x8, w);
      }

    const unsigned vb = (unsigned)(size_t)((const char*)&Vlds[cur][0]) + vlane;
    u32x2 va[2][4][2];
    TRR(va[0][0][0], vb, "0");    TRR(va[0][0][1], vb, "512");
    TRR(va[0][1][0], vb, "2048"); TRR(va[0][1][1], vb, "2560");
    TRR(va[0][2][0], vb, "4096"); TRR(va[0][2][1], vb, "4608");
    TRR(va[0][3][0], vb, "6144"); TRR(va[0][3][1], vb, "6656");
    TRR(va[1][0][0], vb, "256");  TRR(va[1][0][1], vb, "768");
    TRR(va[1][1][0], vb, "2304"); TRR(va[1][1][1], vb, "2816");
    TRR(va[1][2][0], vb, "4352"); TRR(va[1][2][1], vb, "4864");
    TRR(va[1][3][0], vb, "6400"); TRR(va[1][3][1], vb, "6912");
    asm volatile("s_waitcnt lgkmcnt(0)" ::: "memory");
    __builtin_amdgcn_sched_barrier(0);
#pragma unroll
    for (int k0i = 0; k0i < 4; ++k0i) {
      u32x4 w0 = {va[0][k0i][0][0], va[0][k0i][0][1], va[0][k0i][1][0], va[0][k0i][1][1]};
      u32x4 w1 = {va[1][k0i][0][0], va[1][k0i][0][1], va[1][k0i][1][0], va[1][k0i][1][1]};
      acc0 = MFMA32(__builtin_bit_cast(s16x8, w0), pf[k0i], acc0);
      acc1 = MFMA32(__builtin_bit_cast(s16x8, w1), pf[k0i], acc1);
    }

    if (t < 31) {
      char* kld = (char*)&Klds[cur ^ 1][0];
      char* vld = (char*)&Vlds[cur ^ 1][0];
      *(s16x8*)(kld + kb0) = kn0;
      *(s16x8*)(kld + kb1) = kn1;
      *(s16x8*)(vld + vb0w) = vn0;
      *(s16x8*)(vld + vb1w) = vn1;
    }
  }

  const float inv = 1.0f / lsum;
  acc0 *= inv;
  acc1 *= inv;
  float* op = out + ((size_t)bz * 2048 + q0w + l31) * 1024 + head * 64;
#pragma unroll
  for (int c = 0; c < 4; ++c) {
    f32x4u v0 = {acc0[4 * c + 0], acc0[4 * c + 1], acc0[4 * c + 2], acc0[4 * c + 3]};
    f32x4u v1 = {acc1[4 * c + 0], acc1[4 * c + 1], acc1[4 * c + 2], acc1[4 * c + 3]};
    *(f32x4u*)(op + 8 * c + 4 * hi) = v0;
    *(f32x4u*)(op + 32 + 8 * c + 4 * hi) = v1;
  }
}

extern "C" void kernel_launch(void* const* d_in, const int* in_sizes, int n_in,
                              void* d_out, int out_size, void* d_ws, size_t ws_size,
                              hipStream_t stream) {
  const float* query = (const float*)d_in[0];
  const float* key   = (const float*)d_in[1];
  const float* value = (const float*)d_in[2];
  const float* Wq = (const float*)d_in[3];
  const float* bq = (const float*)d_in[4];
  const float* Wk = (const float*)d_in[5];
  const float* bk = (const float*)d_in[6];
  const float* Wv = (const float*)d_in[7];
  const float* bv = (const float*)d_in[8];
  float* out = (float*)d_out;

  short* Qw = (short*)d_ws;  // [3][4096][1024] bf16 outputs (Q pre-scaled 1/8)
  short* Kw = Qw + (size_t)4096 * 1024;
  short* Vw = Kw + (size_t)4096 * 1024;
  short* Xb = Vw + (size_t)4096 * 1024;  // [3][4096][1024] bf16 inputs
  short* Wb = Xb + (size_t)3 * 4096 * 1024;  // [3][1024][1024] bf16 weights

  const size_t need = ((size_t)6 * 4096 * 1024 + (size_t)3 * 1024 * 1024) * 2;

  if (ws_size >= need) {
    CvtArgs ca;
    ca.X[0] = query; ca.X[1] = key; ca.X[2] = value;
    ca.W[0] = Wq; ca.W[1] = Wk; ca.W[2] = Wv;
    ca.Xb = Xb; ca.Wb = Wb;
    cvt_kernel<<<7680, 256, 0, stream>>>(ca);

    Gemm2Args ga;
    ga.Xb = Xb; ga.Wb = Wb;
    ga.Bv[0] = bq; ga.Bv[1] = bk; ga.Bv[2] = bv;
    ga.Y[0] = Qw; ga.Y[1] = Kw; ga.Y[2] = Vw;
    ga.scale[0] = 0.125f; ga.scale[1] = 1.0f; ga.scale[2] = 1.0f;
    qkv_gemm_bf16<<<768, 256, 0, stream>>>(ga);
  } else {
    ProjArgs pa;
    pa.X[0] = query; pa.X[1] = key; pa.X[2] = value;
    pa.W[0] = Wq; pa.W[1] = Wk; pa.W[2] = Wv;
    pa.Bv[0] = bq; pa.Bv[1] = bk; pa.Bv[2] = bv;
    pa.Y[0] = Qw; pa.Y[1] = Kw; pa.Y[2] = Vw;
    pa.scale[0] = 0.125f; pa.scale[1] = 1.0f; pa.scale[2] = 1.0f;
    qkv_proj_fallback<<<dim3(1024 / PBN, 4096 / PBM, 3), 256, 0, stream>>>(pa);
  }

  attn_kernel<<<dim3(16, 2, 16), 256, 0, stream>>>(Qw, Kw, Vw, out);
}

// Round 7
// 116.224 us; speedup vs baseline: 1.7460x; 1.1075x over previous
//
#include <hip/hip_runtime.h>

// B=2, S=2048, H=1024, NH=16, HD=64
// Reference reshape [B,S,H]->[B,NH,S,HD] is a VIEW: head n = flat chunk
// [n*S*HD, (n+1)*S*HD) per batch, i.e. a [2048,64] row-major block.
// out[b,q,n*64+d] = softmax_k(Q_n[q,:]·K_n[k,:]/8) @ V_n[k,d]
// Q is pre-scaled by 0.125*log2(e) so softmax runs in exp2 domain.

typedef short s16x8 __attribute__((ext_vector_type(8)));
typedef float f32x4 __attribute__((ext_vector_type(4)));
typedef float f32x16 __attribute__((ext_vector_type(16)));
typedef unsigned int u32x2 __attribute__((ext_vector_type(2)));
typedef unsigned int u32x4 __attribute__((ext_vector_type(4)));
typedef float f32x4u __attribute__((ext_vector_type(4), aligned(4)));

#define MFMA16(a, b, c) __builtin_amdgcn_mfma_f32_16x16x32_bf16((a), (b), (c), 0, 0, 0)
#define MFMA32(a, b, c) __builtin_amdgcn_mfma_f32_32x32x16_bf16((a), (b), (c), 0, 0, 0)

__device__ __forceinline__ short f2bf(float f) {
  unsigned u = __builtin_bit_cast(unsigned, f);
  u = (u + 0x7fffu + ((u >> 16) & 1u)) >> 16;
  return (short)u;
}

__device__ __forceinline__ float exp2v(float x) {  // v_exp_f32 = 2^x
  float r;
  asm("v_exp_f32 %0, %1" : "=v"(r) : "v"(x));
  return r;
}

#define QSCALE (0.125f * 1.44269504088896340736f)

// ================= Kernel 0: fp32 -> bf16 convert (X[3] then W[3]) =========
struct CvtArgs {
  const float* X[3];
  const float* W[3];
  short* Xb;  // [3][4096][1024]
  short* Wb;  // [3][1024][1024]
};

__global__ __launch_bounds__(256) void cvt_kernel(CvtArgs a) {
  const size_t t = (size_t)blockIdx.x * 256 + threadIdx.x;
  const size_t e = t * 8;
  const float* src;
  short* dst;
  size_t off;
  if (e < (size_t)3 * 4194304) {
    src = a.X[e >> 22];
    off = e & 4194303;
    dst = a.Xb + e;
  } else {
    const size_t e2 = e - (size_t)3 * 4194304;
    src = a.W[e2 >> 20];
    off = e2 & 1048575;
    dst = a.Wb + e2;
  }
  f32x4 v0 = *(const f32x4*)(src + off);
  f32x4 v1 = *(const f32x4*)(src + off + 4);
  s16x8 o;
#pragma unroll
  for (int j = 0; j < 4; ++j) { o[j] = f2bf(v0[j]); o[j + 4] = f2bf(v1[j]); }
  *(s16x8*)dst = o;
}

// ================= Kernel 1b: bf16 GEMM, dbuf + counted vmcnt ==============
// Y[z] = bf16((Xb[z] @ Wb[z]^T + b[z]) * scale[z]); 128x128 tile, BK=64,
// global_load_lds width-16, double-buffered LDS, s_waitcnt vmcnt(8) so the
// next tile's 8 loads stay in flight across the barrier (T4).
struct Gemm2Args {
  const short* Xb;
  const short* Wb;
  const float* Bv[3];
  short* Y[3];
  float scale[3];
};

__global__ __launch_bounds__(256) void qkv_gemm_bf16(Gemm2Args a) {
  // T1 swizzle: nwg=768, cpx=96 -> consecutive logical ids share an XCD L2.
  const int L = (blockIdx.x & 7) * 96 + (blockIdx.x >> 3);
  const int n_t = L & 7;
  const int m_t = (L >> 3) & 31;
  const int z = L >> 8;

  const short* __restrict__ Xz = a.Xb + (size_t)z * 4096 * 1024;
  const short* __restrict__ Wz = a.Wb + (size_t)z * 1024 * 1024;
  const float* __restrict__ Bv = a.Bv[z];
  short* __restrict__ Y = a.Y[z];
  const float scale = a.scale[z];

  __shared__ __align__(16) short Smem[2][2][8192];  // [buf][A/B][128*64], 64KB

  const int tid = threadIdx.x;
  const int lane = tid & 63;
  const int wave = tid >> 6;
  const int m0 = m_t * 128;
  const int n0 = n_t * 128;
  const int moff = (wave >> 1) * 64;
  const int noff = (wave & 1) * 64;
  const int fr = lane & 15;
  const int fk = (lane >> 4) * 8;

  const int srow = lane >> 3;
  const int scol = (lane & 7) * 8;

  f32x4 acc[4][4] = {};

  auto stage = [&](int buf, int k0) {
#pragma unroll
    for (int i = 0; i < 4; ++i) {
      const int c = wave * 4 + i;
      const short* ga = Xz + (size_t)(m0 + c * 8 + srow) * 1024 + k0 + scol;
      const short* gb = Wz + (size_t)(n0 + c * 8 + srow) * 1024 + k0 + scol;
      __builtin_amdgcn_global_load_lds(
          (const __attribute__((address_space(1))) unsigned int*)ga,
          (__attribute__((address_space(3))) unsigned int*)&Smem[buf][0][c * 512], 16, 0, 0);
      __builtin_amdgcn_global_load_lds(
          (const __attribute__((address_space(1))) unsigned int*)gb,
          (__attribute__((address_space(3))) unsigned int*)&Smem[buf][1][c * 512], 16, 0, 0);
    }
  };

  stage(0, 0);
  for (int t = 0; t < 16; ++t) {
    const int buf = t & 1;
    if (t < 15) {
      stage(buf ^ 1, (t + 1) * 64);
      asm volatile("s_waitcnt vmcnt(8)" ::: "memory");  // tile t done, t+1 in flight
    } else {
      asm volatile("s_waitcnt vmcnt(0)" ::: "memory");
    }
    __builtin_amdgcn_s_barrier();
    __builtin_amdgcn_sched_barrier(0);

    const short* Asb = &Smem[buf][0][0];
    const short* Bsb = &Smem[buf][1][0];
#pragma unroll
    for (int kk = 0; kk < 64; kk += 32) {
      s16x8 af[4], bf[4];
#pragma unroll
      for (int i = 0; i < 4; ++i) af[i] = *(const s16x8*)&Asb[(moff + i * 16 + fr) * 64 + kk + fk];
#pragma unroll
      for (int j = 0; j < 4; ++j) bf[j] = *(const s16x8*)&Bsb[(noff + j * 16 + fr) * 64 + kk + fk];
#pragma unroll
      for (int i = 0; i < 4; ++i)
#pragma unroll
        for (int j = 0; j < 4; ++j)
          acc[i][j] = MFMA16(af[i], bf[j], acc[i][j]);
    }
    __builtin_amdgcn_s_barrier();
    __builtin_amdgcn_sched_barrier(0);
  }

  // epilogue: acc -> padded LDS (C layout) -> coalesced b128 row stores
  short* Cs = &Smem[0][0][0];  // scratch [128][136] shorts = 34816B <= 64KB
  const int l16 = lane >> 4;
#pragma unroll
  for (int j = 0; j < 4; ++j) {
    const int col = noff + j * 16 + fr;
    const float bias = Bv[n0 + col];
#pragma unroll
    for (int i = 0; i < 4; ++i) {
      const int rowb = moff + i * 16 + l16 * 4;
#pragma unroll
      for (int r = 0; r < 4; ++r)
        Cs[(rowb + r) * 136 + col] = f2bf((acc[i][j][r] + bias) * scale);
    }
  }
  __syncthreads();
  {
    const int row = tid >> 1;
    const int c0 = (tid & 1) * 64;
    short* dst = Y + (size_t)(m0 + row) * 1024 + n0 + c0;
    const short* src = &Cs[row * 136 + c0];
#pragma unroll
    for (int p = 0; p < 8; ++p)
      *(s16x8*)(dst + p * 8) = *(const s16x8*)(src + p * 8);
  }
}

// ================= Kernel 1 (fallback, fp32 inputs) ========================
struct ProjArgs {
  const float* X[3];
  const float* W[3];
  const float* Bv[3];
  short* Y[3];
  float scale[3];
};

#define PBM 128
#define PBN 128
#define PBK 32
#define PLD (PBK + 8)

__global__ __launch_bounds__(256) void qkv_proj_fallback(ProjArgs args) {
  const int z = blockIdx.z;
  const float* __restrict__ X = args.X[z];
  const float* __restrict__ W = args.W[z];
  const float* __restrict__ Bv = args.Bv[z];
  short* __restrict__ Y = args.Y[z];
  const float scale = args.scale[z];

  __shared__ __align__(16) short As[PBM][PLD];
  __shared__ __align__(16) short Bs[PBN][PLD];

  const int tid = threadIdx.x;
  const int lane = tid & 63;
  const int wave = tid >> 6;
  const int m0 = blockIdx.y * PBM;
  const int n0 = blockIdx.x * PBN;
  const int moff = (wave >> 1) * 64;
  const int noff = (wave & 1) * 64;
  const int fr = lane & 15;
  const int fk = (lane >> 4) * 8;

  const int srow = tid >> 1;
  const int scol = (tid & 1) * 16;

  f32x4 acc[4][4] = {};

  const float* ap = X + (size_t)(m0 + srow) * 1024 + scol;
  const float* bp = W + (size_t)(n0 + srow) * 1024 + scol;

  for (int k0 = 0; k0 < 1024; k0 += PBK) {
    f32x4 a0 = *(const f32x4*)(ap + k0);
    f32x4 a1 = *(const f32x4*)(ap + k0 + 4);
    f32x4 a2 = *(const f32x4*)(ap + k0 + 8);
    f32x4 a3 = *(const f32x4*)(ap + k0 + 12);
    f32x4 b0 = *(const f32x4*)(bp + k0);
    f32x4 b1 = *(const f32x4*)(bp + k0 + 4);
    f32x4 b2 = *(const f32x4*)(bp + k0 + 8);
    f32x4 b3 = *(const f32x4*)(bp + k0 + 12);

    s16x8 sa0, sa1, sb0, sb1;
#pragma unroll
    for (int j = 0; j < 4; ++j) {
      sa0[j] = f2bf(a0[j]); sa0[j + 4] = f2bf(a1[j]);
      sa1[j] = f2bf(a2[j]); sa1[j + 4] = f2bf(a3[j]);
      sb0[j] = f2bf(b0[j]); sb0[j + 4] = f2bf(b1[j]);
      sb1[j] = f2bf(b2[j]); sb1[j + 4] = f2bf(b3[j]);
    }

    __syncthreads();
    *(s16x8*)&As[srow][scol]     = sa0;
    *(s16x8*)&As[srow][scol + 8] = sa1;
    *(s16x8*)&Bs[srow][scol]     = sb0;
    *(s16x8*)&Bs[srow][scol + 8] = sb1;
    __syncthreads();

    s16x8 af[4], bfm[4];
#pragma unroll
    for (int i = 0; i < 4; ++i) af[i] = *(const s16x8*)&As[moff + i * 16 + fr][fk];
#pragma unroll
    for (int j = 0; j < 4; ++j) bfm[j] = *(const s16x8*)&Bs[noff + j * 16 + fr][fk];
#pragma unroll
    for (int i = 0; i < 4; ++i)
#pragma unroll
      for (int j = 0; j < 4; ++j)
        acc[i][j] = MFMA16(af[i], bfm[j], acc[i][j]);
  }

#pragma unroll
  for (int j = 0; j < 4; ++j) {
    const int col = n0 + noff + j * 16 + fr;
    const float bias = Bv[col];
#pragma unroll
    for (int i = 0; i < 4; ++i) {
      const int rowb = m0 + moff + i * 16 + (lane >> 4) * 4;
#pragma unroll
      for (int r = 0; r < 4; ++r) {
        Y[(size_t)(rowb + r) * 1024 + col] = f2bf((acc[i][j][r] + bias) * scale);
      }
    }
  }
}

// ================= Kernel 2: flash attention (exp2-domain softmax) =========
#define TRR(dst, base, OFF) \
  asm volatile("ds_read_b64_tr_b16 %0, %1 offset:" OFF : "=v"(dst) : "v"(base))

__global__ __launch_bounds__(256, 2) void attn_kernel(
    const short* __restrict__ Qb, const short* __restrict__ Kb,
    const short* __restrict__ Vb, float* __restrict__ out) {
  const int head = blockIdx.x;  // 0..15
  const int bz = blockIdx.y;    // 0..1
  const int qb = blockIdx.z;    // 0..15

  const size_t hb = (size_t)bz * (2048 * 1024) + (size_t)head * (2048 * 64);
  const short* __restrict__ Qh = Qb + hb;
  const short* __restrict__ Kh = Kb + hb;
  const short* __restrict__ Vh = Vb + hb;

  __shared__ __align__(16) short Klds[2][4096];
  __shared__ __align__(16) short Vlds[2][4096];

  const int tid = threadIdx.x;
  const int lane = tid & 63;
  const int wave = tid >> 6;
  const int l31 = lane & 31;
  const int hi = lane >> 5;

  const int q0w = qb * 128 + wave * 32;
  s16x8 qf[4];
#pragma unroll
  for (int f = 0; f < 4; ++f)
    qf[f] = *(const s16x8*)(Qh + (size_t)(q0w + l31) * 64 + f * 16 + hi * 8);

  const int kr = tid >> 2;
  const int kc = (tid & 3) * 16;
  const int ksw = (kr & 7) << 4;
  const int kb0 = kr * 128 + ((kc * 2) ^ ksw);
  const int kb1 = kr * 128 + ((kc * 2 + 16) ^ ksw);
  const int vd0 = (tid & 3) * 16 + (((tid >> 4) & 1) * 8);
  const int vd1 = vd0 ^ 8;
  const int vb0w = ((kr >> 2) * 4 + (vd0 >> 4)) * 128 + (kr & 3) * 32 + (vd0 & 15) * 2;
  const int vb1w = ((kr >> 2) * 4 + (vd1 >> 4)) * 128 + (kr & 3) * 32 + (vd1 & 15) * 2;

  int cXor[4];
#pragma unroll
  for (int f = 0; f < 4; ++f) cXor[f] = ((f * 32 + hi * 16) ^ ((l31 & 7) << 4));

  const unsigned vlane = (unsigned)(hi * 1024 + ((l31 >> 4) * 128) + (lane & 15) * 8);

  s16x8 kn0 = *(const s16x8*)(Kh + kr * 64 + kc);
  s16x8 kn1 = *(const s16x8*)(Kh + kr * 64 + kc + 8);
  s16x8 vn0 = *(const s16x8*)(Vh + kr * 64 + vd0);
  s16x8 vn1 = *(const s16x8*)(Vh + kr * 64 + vd1);
  *(s16x8*)((char*)&Klds[0][0] + kb0) = kn0;
  *(s16x8*)((char*)&Klds[0][0] + kb1) = kn1;
  *(s16x8*)((char*)&Vlds[0][0] + vb0w) = vn0;
  *(s16x8*)((char*)&Vlds[0][0] + vb1w) = vn1;

  float m = -1e30f, lsum = 0.f;
  f32x16 acc0 = {}, acc1 = {};

  for (int t = 0; t < 32; ++t) {
    __syncthreads();
    const int cur = t & 1;

    if (t < 31) {
      const short* kg = Kh + (size_t)(t + 1) * 4096 + kr * 64 + kc;
      kn0 = *(const s16x8*)kg;
      kn1 = *(const s16x8*)(kg + 8);
      const short* vg = Vh + (size_t)(t + 1) * 4096 + kr * 64;
      vn0 = *(const s16x8*)(vg + vd0);
      vn1 = *(const s16x8*)(vg + vd1);
    }

    const char* kl = (const char*)&Klds[cur][0];
    f32x16 et0 = {}, et1 = {};
    __builtin_amdgcn_s_setprio(1);
#pragma unroll
    for (int f = 0; f < 4; ++f) {
      s16x8 kf = *(const s16x8*)(kl + l31 * 128 + cXor[f]);
      et0 = MFMA32(kf, qf[f], et0);
    }
#pragma unroll
    for (int f = 0; f < 4; ++f) {
      s16x8 kf = *(const s16x8*)(kl + 4096 + l31 * 128 + cXor[f]);
      et1 = MFMA32(kf, qf[f], et1);
    }
    __builtin_amdgcn_s_setprio(0);

    // ---- online softmax, exp2 domain, defer-max (THR=8 -> P <= 256)
    float mx[16];
#pragma unroll
    for (int r = 0; r < 16; ++r) mx[r] = fmaxf(et0[r], et1[r]);
#pragma unroll
    for (int s2 = 8; s2 >= 1; s2 >>= 1)
#pragma unroll
      for (int r = 0; r < 8; ++r)
        if (r < s2) mx[r] = fmaxf(mx[r], mx[r + s2]);
    if (__any(mx[0] > m + 8.f)) {
      const float mt = fmaxf(mx[0], __shfl_xor(mx[0], 32));
      const float mnew = fmaxf(m, mt);
      const float corr = exp2v(m - mnew);
      lsum *= corr;
      acc0 *= corr;
      acc1 *= corr;
      m = mnew;
    }

    float p0a[16], p1a[16], sm[16];
#pragma unroll
    for (int r = 0; r < 16; ++r) {
      p0a[r] = exp2v(et0[r] - m);
      p1a[r] = exp2v(et1[r] - m);
      sm[r] = p0a[r] + p1a[r];
    }
#pragma unroll
    for (int s2 = 8; s2 >= 1; s2 >>= 1)
#pragma unroll
      for (int r = 0; r < 8; ++r)
        if (r < s2) sm[r] += sm[r + s2];
    lsum += sm[0] + __shfl_xor(sm[0], 32);

    // ---- pack P^T -> bf16; xr[T][c] = k pair {8c+4hi+0,1}+32T, yr = {+2,3}
    unsigned xr[2][4], yr[2][4];
#pragma unroll
    for (int c = 0; c < 4; ++c) {
      asm("v_cvt_pk_bf16_f32 %0, %1, %2" : "=v"(xr[0][c]) : "v"(p0a[4 * c + 0]), "v"(p0a[4 * c + 1]));
      asm("v_cvt_pk_bf16_f32 %0, %1, %2" : "=v"(yr[0][c]) : "v"(p0a[4 * c + 2]), "v"(p0a[4 * c + 3]));
      asm("v_cvt_pk_bf16_f32 %0, %1, %2" : "=v"(xr[1][c]) : "v"(p1a[4 * c + 0]), "v"(p1a[4 * c + 1]));
      asm("v_cvt_pk_bf16_f32 %0, %1, %2" : "=v"(yr[1][c]) : "v"(p1a[4 * c + 2]), "v"(p1a[4 * c + 3]));
    }
    // permlane32_swap(a,b): a.hi32lanes <-> b.lo32lanes. swap(xr[2u],xr[2u+1])
    // leaves w0 in the first reg and w2 in the second, for BOTH halves.
    s16x8 pf[4];
#pragma unroll
    for (int T = 0; T < 2; ++T)
#pragma unroll
      for (int u = 0; u < 2; ++u) {
        unsigned w0 = xr[T][2 * u], w2 = xr[T][2 * u + 1];
        unsigned w1 = yr[T][2 * u], w3 = yr[T][2 * u + 1];
        asm("v_permlane32_swap_b32 %0, %1" : "+v"(w0), "+v"(w2));
        asm("v_permlane32_swap_b32 %0, %1" : "+v"(w1), "+v"(w3));
        u32x4 w = {w0, w1, w2, w3};
        pf[2 * T + u] = __builtin_bit_cast(s16x8, w);
      }

    const unsigned vb = (unsigned)(size_t)((const char*)&Vlds[cur][0]) + vlane;
    u32x2 va[2][4][2];
    TRR(va[0][0][0], vb, "0");    TRR(va[0][0][1], vb, "512");
    TRR(va[0][1][0], vb, "2048"); TRR(va[0][1][1], vb, "2560");
    TRR(va[0][2][0], vb, "4096"); TRR(va[0][2][1], vb, "4608");
    TRR(va[0][3][0], vb, "6144"); TRR(va[0][3][1], vb, "6656");
    TRR(va[1][0][0], vb, "256");  TRR(va[1][0][1], vb, "768");
    TRR(va[1][1][0], vb, "2304"); TRR(va[1][1][1], vb, "2816");
    TRR(va[1][2][0], vb, "4352"); TRR(va[1][2][1], vb, "4864");
    TRR(va[1][3][0], vb, "6400"); TRR(va[1][3][1], vb, "6912");
    asm volatile("s_waitcnt lgkmcnt(0)" ::: "memory");
    __builtin_amdgcn_sched_barrier(0);
    __builtin_amdgcn_s_setprio(1);
#pragma unroll
    for (int k0i = 0; k0i < 4; ++k0i) {
      u32x4 w0 = {va[0][k0i][0][0], va[0][k0i][0][1], va[0][k0i][1][0], va[0][k0i][1][1]};
      u32x4 w1 = {va[1][k0i][0][0], va[1][k0i][0][1], va[1][k0i][1][0], va[1][k0i][1][1]};
      acc0 = MFMA32(__builtin_bit_cast(s16x8, w0), pf[k0i], acc0);
      acc1 = MFMA32(__builtin_bit_cast(s16x8, w1), pf[k0i], acc1);
    }
    __builtin_amdgcn_s_setprio(0);

    if (t < 31) {
      char* kld = (char*)&Klds[cur ^ 1][0];
      char* vld = (char*)&Vlds[cur ^ 1][0];
      *(s16x8*)(kld + kb0) = kn0;
      *(s16x8*)(kld + kb1) = kn1;
      *(s16x8*)(vld + vb0w) = vn0;
      *(s16x8*)(vld + vb1w) = vn1;
    }
  }

  const float inv = 1.0f / lsum;
  acc0 *= inv;
  acc1 *= inv;
  float* op = out + ((size_t)bz * 2048 + q0w + l31) * 1024 + head * 64;
#pragma unroll
  for (int c = 0; c < 4; ++c) {
    f32x4u v0 = {acc0[4 * c + 0], acc0[4 * c + 1], acc0[4 * c + 2], acc0[4 * c + 3]};
    f32x4u v1 = {acc1[4 * c + 0], acc1[4 * c + 1], acc1[4 * c + 2], acc1[4 * c + 3]};
    *(f32x4u*)(op + 8 * c + 4 * hi) = v0;
    *(f32x4u*)(op + 32 + 8 * c + 4 * hi) = v1;
  }
}

extern "C" void kernel_launch(void* const* d_in, const int* in_sizes, int n_in,
                              void* d_out, int out_size, void* d_ws, size_t ws_size,
                              hipStream_t stream) {
  const float* query = (const float*)d_in[0];
  const float* key   = (const float*)d_in[1];
  const float* value = (const float*)d_in[2];
  const float* Wq = (const float*)d_in[3];
  const float* bq = (const float*)d_in[4];
  const float* Wk = (const float*)d_in[5];
  const float* bk = (const float*)d_in[6];
  const float* Wv = (const float*)d_in[7];
  const float* bv = (const float*)d_in[8];
  float* out = (float*)d_out;

  short* Qw = (short*)d_ws;  // [3][4096][1024] bf16 outputs (Q scaled 0.125*log2e)
  short* Kw = Qw + (size_t)4096 * 1024;
  short* Vw = Kw + (size_t)4096 * 1024;
  short* Xb = Vw + (size_t)4096 * 1024;      // [3][4096][1024] bf16 inputs
  short* Wb = Xb + (size_t)3 * 4096 * 1024;  // [3][1024][1024] bf16 weights

  const size_t need = ((size_t)6 * 4096 * 1024 + (size_t)3 * 1024 * 1024) * 2;

  if (ws_size >= need) {
    CvtArgs ca;
    ca.X[0] = query; ca.X[1] = key; ca.X[2] = value;
    ca.W[0] = Wq; ca.W[1] = Wk; ca.W[2] = Wv;
    ca.Xb = Xb; ca.Wb = Wb;
    cvt_kernel<<<7680, 256, 0, stream>>>(ca);

    Gemm2Args ga;
    ga.Xb = Xb; ga.Wb = Wb;
    ga.Bv[0] = bq; ga.Bv[1] = bk; ga.Bv[2] = bv;
    ga.Y[0] = Qw; ga.Y[1] = Kw; ga.Y[2] = Vw;
    ga.scale[0] = QSCALE; ga.scale[1] = 1.0f; ga.scale[2] = 1.0f;
    qkv_gemm_bf16<<<768, 256, 0, stream>>>(ga);
  } else {
    ProjArgs pa;
    pa.X[0] = query; pa.X[1] = key; pa.X[2] = value;
    pa.W[0] = Wq; pa.W[1] = Wk; pa.W[2] = Wv;
    pa.Bv[0] = bq; pa.Bv[1] = bk; pa.Bv[2] = bv;
    pa.Y[0] = Qw; pa.Y[1] = Kw; pa.Y[2] = Vw;
    pa.scale[0] = QSCALE; pa.scale[1] = 1.0f; pa.scale[2] = 1.0f;
    qkv_proj_fallback<<<dim3(1024 / PBN, 4096 / PBM, 3), 256, 0, stream>>>(pa);
  }

  attn_kernel<<<dim3(16, 2, 16), 256, 0, stream>>>(Qw, Kw, Vw, out);
}

// Round 8
// 114.737 us; speedup vs baseline: 1.7686x; 1.0130x over previous
//
#include <hip/hip_runtime.h>

// B=2, S=2048, H=1024, NH=16, HD=64
// Reference reshape [B,S,H]->[B,NH,S,HD] is a VIEW: head n = flat chunk
// [n*S*HD, (n+1)*S*HD) per batch, i.e. a [2048,64] row-major block.
// out[b,q,n*64+d] = softmax_k(Q_n[q,:]·K_n[k,:]/8) @ V_n[k,d]
// Q is pre-scaled by 0.125*log2(e) so softmax runs in exp2 domain.

typedef short s16x8 __attribute__((ext_vector_type(8)));
typedef float f32x4 __attribute__((ext_vector_type(4)));
typedef float f32x16 __attribute__((ext_vector_type(16)));
typedef unsigned int u32x2 __attribute__((ext_vector_type(2)));
typedef unsigned int u32x4 __attribute__((ext_vector_type(4)));
typedef float f32x4u __attribute__((ext_vector_type(4), aligned(4)));

#define MFMA16(a, b, c) __builtin_amdgcn_mfma_f32_16x16x32_bf16((a), (b), (c), 0, 0, 0)
#define MFMA32(a, b, c) __builtin_amdgcn_mfma_f32_32x32x16_bf16((a), (b), (c), 0, 0, 0)

__device__ __forceinline__ short f2bf(float f) {
  unsigned u = __builtin_bit_cast(unsigned, f);
  u = (u + 0x7fffu + ((u >> 16) & 1u)) >> 16;
  return (short)u;
}

__device__ __forceinline__ float exp2v(float x) {  // v_exp_f32 = 2^x
  float r;
  asm("v_exp_f32 %0, %1" : "=v"(r) : "v"(x));
  return r;
}

#define QSCALE (0.125f * 1.44269504088896340736f)

// ================= Kernel 0: fp32 -> bf16 convert (X[3] then W[3]) =========
struct CvtArgs {
  const float* X[3];
  const float* W[3];
  short* Xb;  // [3][4096][1024]
  short* Wb;  // [3][1024][1024]
};

__global__ __launch_bounds__(256) void cvt_kernel(CvtArgs a) {
  const size_t t = (size_t)blockIdx.x * 256 + threadIdx.x;
  const size_t e = t * 8;
  const float* src;
  short* dst;
  size_t off;
  if (e < (size_t)3 * 4194304) {
    src = a.X[e >> 22];
    off = e & 4194303;
    dst = a.Xb + e;
  } else {
    const size_t e2 = e - (size_t)3 * 4194304;
    src = a.W[e2 >> 20];
    off = e2 & 1048575;
    dst = a.Wb + e2;
  }
  f32x4 v0 = *(const f32x4*)(src + off);
  f32x4 v1 = *(const f32x4*)(src + off + 4);
  s16x8 o;
#pragma unroll
  for (int j = 0; j < 4; ++j) { o[j] = f2bf(v0[j]); o[j + 4] = f2bf(v1[j]); }
  *(s16x8*)dst = o;
}

// ================= Kernel 1b: bf16 GEMM, dbuf + vmcnt + swizzled LDS =======
// Y[z] = bf16((Xb[z] @ Wb[z]^T + b[z]) * scale[z]); 128x128 tile, BK=64,
// global_load_lds width-16 with INVERSE-SWIZZLED source (rule #21): LDS
// content at (row, col) = global (row, col ^ (row&7)*8); reads XOR back ->
// conflict-free ds_read_b128 (2-way max).
struct Gemm2Args {
  const short* Xb;
  const short* Wb;
  const float* Bv[3];
  short* Y[3];
  float scale[3];
};

__global__ __launch_bounds__(256) void qkv_gemm_bf16(Gemm2Args a) {
  // T1 swizzle: nwg=768, cpx=96 -> consecutive logical ids share an XCD L2.
  const int L = (blockIdx.x & 7) * 96 + (blockIdx.x >> 3);
  const int n_t = L & 7;
  const int m_t = (L >> 3) & 31;
  const int z = L >> 8;

  const short* __restrict__ Xz = a.Xb + (size_t)z * 4096 * 1024;
  const short* __restrict__ Wz = a.Wb + (size_t)z * 1024 * 1024;
  const float* __restrict__ Bv = a.Bv[z];
  short* __restrict__ Y = a.Y[z];
  const float scale = a.scale[z];

  __shared__ __align__(16) short Smem[2][2][8192];  // [buf][A/B][128*64], 64KB

  const int tid = threadIdx.x;
  const int lane = tid & 63;
  const int wave = tid >> 6;
  const int m0 = m_t * 128;
  const int n0 = n_t * 128;
  const int moff = (wave >> 1) * 64;
  const int noff = (wave & 1) * 64;
  const int fr = lane & 15;
  const int fk = (lane >> 4) * 8;
  const int fsw = (fr & 7) * 8;  // read-side XOR (shorts)

  const int srow = lane >> 3;
  const int scolX = ((lane & 7) ^ (lane >> 3)) * 8;  // inverse-swizzled source col

  f32x4 acc[4][4] = {};

  auto stage = [&](int buf, int k0) {
#pragma unroll
    for (int i = 0; i < 4; ++i) {
      const int c = wave * 4 + i;
      const short* ga = Xz + (size_t)(m0 + c * 8 + srow) * 1024 + k0 + scolX;
      const short* gb = Wz + (size_t)(n0 + c * 8 + srow) * 1024 + k0 + scolX;
      __builtin_amdgcn_global_load_lds(
          (const __attribute__((address_space(1))) unsigned int*)ga,
          (__attribute__((address_space(3))) unsigned int*)&Smem[buf][0][c * 512], 16, 0, 0);
      __builtin_amdgcn_global_load_lds(
          (const __attribute__((address_space(1))) unsigned int*)gb,
          (__attribute__((address_space(3))) unsigned int*)&Smem[buf][1][c * 512], 16, 0, 0);
    }
  };

  stage(0, 0);
  for (int t = 0; t < 16; ++t) {
    const int buf = t & 1;
    if (t < 15) {
      stage(buf ^ 1, (t + 1) * 64);
      asm volatile("s_waitcnt vmcnt(8)" ::: "memory");  // tile t done, t+1 in flight
    } else {
      asm volatile("s_waitcnt vmcnt(0)" ::: "memory");
    }
    __builtin_amdgcn_s_barrier();
    __builtin_amdgcn_sched_barrier(0);

    const short* Asb = &Smem[buf][0][0];
    const short* Bsb = &Smem[buf][1][0];
#pragma unroll
    for (int kk = 0; kk < 64; kk += 32) {
      s16x8 af[4], bf[4];
#pragma unroll
      for (int i = 0; i < 4; ++i)
        af[i] = *(const s16x8*)&Asb[(moff + i * 16 + fr) * 64 + ((kk + fk) ^ fsw)];
#pragma unroll
      for (int j = 0; j < 4; ++j)
        bf[j] = *(const s16x8*)&Bsb[(noff + j * 16 + fr) * 64 + ((kk + fk) ^ fsw)];
#pragma unroll
      for (int i = 0; i < 4; ++i)
#pragma unroll
        for (int j = 0; j < 4; ++j)
          acc[i][j] = MFMA16(af[i], bf[j], acc[i][j]);
    }
    __builtin_amdgcn_s_barrier();
    __builtin_amdgcn_sched_barrier(0);
  }

  // epilogue: acc -> padded LDS (C layout) -> coalesced b128 row stores
  short* Cs = &Smem[0][0][0];  // scratch [128][136] shorts = 34816B <= 64KB
  const int l16 = lane >> 4;
#pragma unroll
  for (int j = 0; j < 4; ++j) {
    const int col = noff + j * 16 + fr;
    const float bias = Bv[n0 + col];
#pragma unroll
    for (int i = 0; i < 4; ++i) {
      const int rowb = moff + i * 16 + l16 * 4;
#pragma unroll
      for (int r = 0; r < 4; ++r)
        Cs[(rowb + r) * 136 + col] = f2bf((acc[i][j][r] + bias) * scale);
    }
  }
  __syncthreads();
  {
    const int row = tid >> 1;
    const int c0 = (tid & 1) * 64;
    short* dst = Y + (size_t)(m0 + row) * 1024 + n0 + c0;
    const short* src = &Cs[row * 136 + c0];
#pragma unroll
    for (int p = 0; p < 8; ++p)
      *(s16x8*)(dst + p * 8) = *(const s16x8*)(src + p * 8);
  }
}

// ================= Kernel 1 (fallback, fp32 inputs) ========================
struct ProjArgs {
  const float* X[3];
  const float* W[3];
  const float* Bv[3];
  short* Y[3];
  float scale[3];
};

#define PBM 128
#define PBN 128
#define PBK 32
#define PLD (PBK + 8)

__global__ __launch_bounds__(256) void qkv_proj_fallback(ProjArgs args) {
  const int z = blockIdx.z;
  const float* __restrict__ X = args.X[z];
  const float* __restrict__ W = args.W[z];
  const float* __restrict__ Bv = args.Bv[z];
  short* __restrict__ Y = args.Y[z];
  const float scale = args.scale[z];

  __shared__ __align__(16) short As[PBM][PLD];
  __shared__ __align__(16) short Bs[PBN][PLD];

  const int tid = threadIdx.x;
  const int lane = tid & 63;
  const int wave = tid >> 6;
  const int m0 = blockIdx.y * PBM;
  const int n0 = blockIdx.x * PBN;
  const int moff = (wave >> 1) * 64;
  const int noff = (wave & 1) * 64;
  const int fr = lane & 15;
  const int fk = (lane >> 4) * 8;

  const int srow = tid >> 1;
  const int scol = (tid & 1) * 16;

  f32x4 acc[4][4] = {};

  const float* ap = X + (size_t)(m0 + srow) * 1024 + scol;
  const float* bp = W + (size_t)(n0 + srow) * 1024 + scol;

  for (int k0 = 0; k0 < 1024; k0 += PBK) {
    f32x4 a0 = *(const f32x4*)(ap + k0);
    f32x4 a1 = *(const f32x4*)(ap + k0 + 4);
    f32x4 a2 = *(const f32x4*)(ap + k0 + 8);
    f32x4 a3 = *(const f32x4*)(ap + k0 + 12);
    f32x4 b0 = *(const f32x4*)(bp + k0);
    f32x4 b1 = *(const f32x4*)(bp + k0 + 4);
    f32x4 b2 = *(const f32x4*)(bp + k0 + 8);
    f32x4 b3 = *(const f32x4*)(bp + k0 + 12);

    s16x8 sa0, sa1, sb0, sb1;
#pragma unroll
    for (int j = 0; j < 4; ++j) {
      sa0[j] = f2bf(a0[j]); sa0[j + 4] = f2bf(a1[j]);
      sa1[j] = f2bf(a2[j]); sa1[j + 4] = f2bf(a3[j]);
      sb0[j] = f2bf(b0[j]); sb0[j + 4] = f2bf(b1[j]);
      sb1[j] = f2bf(b2[j]); sb1[j + 4] = f2bf(b3[j]);
    }

    __syncthreads();
    *(s16x8*)&As[srow][scol]     = sa0;
    *(s16x8*)&As[srow][scol + 8] = sa1;
    *(s16x8*)&Bs[srow][scol]     = sb0;
    *(s16x8*)&Bs[srow][scol + 8] = sb1;
    __syncthreads();

    s16x8 af[4], bfm[4];
#pragma unroll
    for (int i = 0; i < 4; ++i) af[i] = *(const s16x8*)&As[moff + i * 16 + fr][fk];
#pragma unroll
    for (int j = 0; j < 4; ++j) bfm[j] = *(const s16x8*)&Bs[noff + j * 16 + fr][fk];
#pragma unroll
    for (int i = 0; i < 4; ++i)
#pragma unroll
      for (int j = 0; j < 4; ++j)
        acc[i][j] = MFMA16(af[i], bfm[j], acc[i][j]);
  }

#pragma unroll
  for (int j = 0; j < 4; ++j) {
    const int col = n0 + noff + j * 16 + fr;
    const float bias = Bv[col];
#pragma unroll
    for (int i = 0; i < 4; ++i) {
      const int rowb = m0 + moff + i * 16 + (lane >> 4) * 4;
#pragma unroll
      for (int r = 0; r < 4; ++r) {
        Y[(size_t)(rowb + r) * 1024 + col] = f2bf((acc[i][j][r] + bias) * scale);
      }
    }
  }
}

// ================= Kernel 2: flash attention, split-K (2 groups x 4 waves) =
// Block: 512 thr. Group g (tid>>8) processes KV tiles [g*16, g*16+16) for the
// same 128 q-rows; groups merge (m,l,O) through LDS at the end. Doubles
// waves/SIMD (2 -> 4) and halves each wave's serial softmax chain.
#define TRR(dst, base, OFF) \
  asm volatile("ds_read_b64_tr_b16 %0, %1 offset:" OFF : "=v"(dst) : "v"(base))

__global__ __launch_bounds__(512, 4) void attn_kernel(
    const short* __restrict__ Qb, const short* __restrict__ Kb,
    const short* __restrict__ Vb, float* __restrict__ out) {
  const int head = blockIdx.x;  // 0..15
  const int bz = blockIdx.y;    // 0..1
  const int qb = blockIdx.z;    // 0..15

  const size_t hb = (size_t)bz * (2048 * 1024) + (size_t)head * (2048 * 64);
  const short* __restrict__ Qh = Qb + hb;
  const short* __restrict__ Kh = Kb + hb;
  const short* __restrict__ Vh = Vb + hb;

  __shared__ __align__(16) short Klds[2][2][4096];  // [group][buf]
  __shared__ __align__(16) short Vlds[2][2][4096];

  const int tid = threadIdx.x;
  const int lane = tid & 63;
  const int g = tid >> 8;         // k-half
  const int gtid = tid & 255;
  const int w4 = (tid >> 6) & 3;  // wave within group -> q sub-block
  const int l31 = lane & 31;
  const int hi = lane >> 5;

  const int q0w = qb * 128 + w4 * 32;
  s16x8 qf[4];
#pragma unroll
  for (int f = 0; f < 4; ++f)
    qf[f] = *(const s16x8*)(Qh + (size_t)(q0w + l31) * 64 + f * 16 + hi * 8);

  // staging mapping (256 threads of a group stage one 64x64 K and V tile)
  const int kr = gtid >> 2;
  const int kc = (gtid & 3) * 16;
  const int ksw = (kr & 7) << 4;
  const int kb0 = kr * 128 + ((kc * 2) ^ ksw);
  const int kb1 = kr * 128 + ((kc * 2 + 16) ^ ksw);
  const int vd0 = (gtid & 3) * 16 + (((gtid >> 4) & 1) * 8);
  const int vd1 = vd0 ^ 8;
  const int vb0w = ((kr >> 2) * 4 + (vd0 >> 4)) * 128 + (kr & 3) * 32 + (vd0 & 15) * 2;
  const int vb1w = ((kr >> 2) * 4 + (vd1 >> 4)) * 128 + (kr & 3) * 32 + (vd1 & 15) * 2;

  int cXor[4];
#pragma unroll
  for (int f = 0; f < 4; ++f) cXor[f] = ((f * 32 + hi * 16) ^ ((l31 & 7) << 4));

  const unsigned vlane = (unsigned)(hi * 1024 + ((l31 >> 4) * 128) + (lane & 15) * 8);

  // prologue: group g stages tile g*16
  const short* Kg0 = Kh + (size_t)(g * 16) * 4096;
  const short* Vg0 = Vh + (size_t)(g * 16) * 4096;
  s16x8 kn0 = *(const s16x8*)(Kg0 + kr * 64 + kc);
  s16x8 kn1 = *(const s16x8*)(Kg0 + kr * 64 + kc + 8);
  s16x8 vn0 = *(const s16x8*)(Vg0 + kr * 64 + vd0);
  s16x8 vn1 = *(const s16x8*)(Vg0 + kr * 64 + vd1);
  *(s16x8*)((char*)&Klds[g][0][0] + kb0) = kn0;
  *(s16x8*)((char*)&Klds[g][0][0] + kb1) = kn1;
  *(s16x8*)((char*)&Vlds[g][0][0] + vb0w) = vn0;
  *(s16x8*)((char*)&Vlds[g][0][0] + vb1w) = vn1;

  float m = -1e30f, lsum = 0.f;
  f32x16 acc0 = {}, acc1 = {};

  for (int t = 0; t < 16; ++t) {
    __syncthreads();
    const int cur = t & 1;

    if (t < 15) {  // prefetch next tile of this group's half
      const short* kg = Kh + (size_t)(g * 16 + t + 1) * 4096 + kr * 64 + kc;
      kn0 = *(const s16x8*)kg;
      kn1 = *(const s16x8*)(kg + 8);
      const short* vg = Vh + (size_t)(g * 16 + t + 1) * 4096 + kr * 64;
      vn0 = *(const s16x8*)(vg + vd0);
      vn1 = *(const s16x8*)(vg + vd1);
    }

    const char* kl = (const char*)&Klds[g][cur][0];
    f32x16 et0 = {}, et1 = {};
    __builtin_amdgcn_s_setprio(1);
#pragma unroll
    for (int f = 0; f < 4; ++f) {
      s16x8 kf = *(const s16x8*)(kl + l31 * 128 + cXor[f]);
      et0 = MFMA32(kf, qf[f], et0);
    }
#pragma unroll
    for (int f = 0; f < 4; ++f) {
      s16x8 kf = *(const s16x8*)(kl + 4096 + l31 * 128 + cXor[f]);
      et1 = MFMA32(kf, qf[f], et1);
    }
    __builtin_amdgcn_s_setprio(0);

    // ---- online softmax, exp2 domain, defer-max (THR=8 -> P <= 256)
    float mx[16];
#pragma unroll
    for (int r = 0; r < 16; ++r) mx[r] = fmaxf(et0[r], et1[r]);
#pragma unroll
    for (int s2 = 8; s2 >= 1; s2 >>= 1)
#pragma unroll
      for (int r = 0; r < 8; ++r)
        if (r < s2) mx[r] = fmaxf(mx[r], mx[r + s2]);
    if (__any(mx[0] > m + 8.f)) {
      const float mt = fmaxf(mx[0], __shfl_xor(mx[0], 32));
      const float mnew = fmaxf(m, mt);
      const float corr = exp2v(m - mnew);
      lsum *= corr;
      acc0 *= corr;
      acc1 *= corr;
      m = mnew;
    }

    float p0a[16], p1a[16], sm[16];
#pragma unroll
    for (int r = 0; r < 16; ++r) {
      p0a[r] = exp2v(et0[r] - m);
      p1a[r] = exp2v(et1[r] - m);
      sm[r] = p0a[r] + p1a[r];
    }
#pragma unroll
    for (int s2 = 8; s2 >= 1; s2 >>= 1)
#pragma unroll
      for (int r = 0; r < 8; ++r)
        if (r < s2) sm[r] += sm[r + s2];
    lsum += sm[0] + __shfl_xor(sm[0], 32);

    // ---- pack P^T -> bf16; permlane32_swap builds both halves' words
    unsigned xr[2][4], yr[2][4];
#pragma unroll
    for (int c = 0; c < 4; ++c) {
      asm("v_cvt_pk_bf16_f32 %0, %1, %2" : "=v"(xr[0][c]) : "v"(p0a[4 * c + 0]), "v"(p0a[4 * c + 1]));
      asm("v_cvt_pk_bf16_f32 %0, %1, %2" : "=v"(yr[0][c]) : "v"(p0a[4 * c + 2]), "v"(p0a[4 * c + 3]));
      asm("v_cvt_pk_bf16_f32 %0, %1, %2" : "=v"(xr[1][c]) : "v"(p1a[4 * c + 0]), "v"(p1a[4 * c + 1]));
      asm("v_cvt_pk_bf16_f32 %0, %1, %2" : "=v"(yr[1][c]) : "v"(p1a[4 * c + 2]), "v"(p1a[4 * c + 3]));
    }
    s16x8 pf[4];
#pragma unroll
    for (int T = 0; T < 2; ++T)
#pragma unroll
      for (int u = 0; u < 2; ++u) {
        unsigned w0 = xr[T][2 * u], w2 = xr[T][2 * u + 1];
        unsigned w1 = yr[T][2 * u], w3 = yr[T][2 * u + 1];
        asm("v_permlane32_swap_b32 %0, %1" : "+v"(w0), "+v"(w2));
        asm("v_permlane32_swap_b32 %0, %1" : "+v"(w1), "+v"(w3));
        u32x4 w = {w0, w1, w2, w3};
        pf[2 * T + u] = __builtin_bit_cast(s16x8, w);
      }

    const unsigned vb = (unsigned)(size_t)((const char*)&Vlds[g][cur][0]) + vlane;
    u32x2 va[2][4][2];
    TRR(va[0][0][0], vb, "0");    TRR(va[0][0][1], vb, "512");
    TRR(va[0][1][0], vb, "2048"); TRR(va[0][1][1], vb, "2560");
    TRR(va[0][2][0], vb, "4096"); TRR(va[0][2][1], vb, "4608");
    TRR(va[0][3][0], vb, "6144"); TRR(va[0][3][1], vb, "6656");
    TRR(va[1][0][0], vb, "256");  TRR(va[1][0][1], vb, "768");
    TRR(va[1][1][0], vb, "2304"); TRR(va[1][1][1], vb, "2816");
    TRR(va[1][2][0], vb, "4352"); TRR(va[1][2][1], vb, "4864");
    TRR(va[1][3][0], vb, "6400"); TRR(va[1][3][1], vb, "6912");
    asm volatile("s_waitcnt lgkmcnt(0)" ::: "memory");
    __builtin_amdgcn_sched_barrier(0);
    __builtin_amdgcn_s_setprio(1);
#pragma unroll
    for (int k0i = 0; k0i < 4; ++k0i) {
      u32x4 w0 = {va[0][k0i][0][0], va[0][k0i][0][1], va[0][k0i][1][0], va[0][k0i][1][1]};
      u32x4 w1 = {va[1][k0i][0][0], va[1][k0i][0][1], va[1][k0i][1][0], va[1][k0i][1][1]};
      acc0 = MFMA32(__builtin_bit_cast(s16x8, w0), pf[k0i], acc0);
      acc1 = MFMA32(__builtin_bit_cast(s16x8, w1), pf[k0i], acc1);
    }
    __builtin_amdgcn_s_setprio(0);

    if (t < 15) {
      char* kld = (char*)&Klds[g][cur ^ 1][0];
      char* vld = (char*)&Vlds[g][cur ^ 1][0];
      *(s16x8*)(kld + kb0) = kn0;
      *(s16x8*)(kld + kb1) = kn1;
      *(s16x8*)(vld + vb0w) = vn0;
      *(s16x8*)(vld + vb1w) = vn1;
    }
  }

  // ---- merge the two k-halves through LDS (reuse K/V buffers)
  __syncthreads();
  float* sc = (float*)&Klds[0][0][0];  // [32][256] floats = 32KB (column-major)
  float* ml = (float*)&Vlds[0][0][0];  // m[256], l[256]
  if (g == 1) {
#pragma unroll
    for (int r = 0; r < 16; ++r) {
      sc[r * 256 + gtid] = acc0[r];
      sc[(16 + r) * 256 + gtid] = acc1[r];
    }
    ml[gtid] = m;
    ml[256 + gtid] = lsum;
  }
  __syncthreads();
  if (g == 0) {
    const float m1 = ml[gtid], l1 = ml[256 + gtid];
    const float mf = fmaxf(m, m1);
    const float c0 = exp2v(m - mf), c1 = exp2v(m1 - mf);
    const float linv = 1.0f / (lsum * c0 + l1 * c1);
    float* op = out + ((size_t)bz * 2048 + q0w + l31) * 1024 + head * 64;
#pragma unroll
    for (int c = 0; c < 4; ++c) {
      f32x4u v0, v1;
#pragma unroll
      for (int r2 = 0; r2 < 4; ++r2) {
        v0[r2] = (acc0[4 * c + r2] * c0 + sc[(4 * c + r2) * 256 + gtid] * c1) * linv;
        v1[r2] = (acc1[4 * c + r2] * c0 + sc[(16 + 4 * c + r2) * 256 + gtid] * c1) * linv;
      }
      *(f32x4u*)(op + 8 * c + 4 * hi) = v0;
      *(f32x4u*)(op + 32 + 8 * c + 4 * hi) = v1;
    }
  }
}

extern "C" void kernel_launch(void* const* d_in, const int* in_sizes, int n_in,
                              void* d_out, int out_size, void* d_ws, size_t ws_size,
                              hipStream_t stream) {
  const float* query = (const float*)d_in[0];
  const float* key   = (const float*)d_in[1];
  const float* value = (const float*)d_in[2];
  const float* Wq = (const float*)d_in[3];
  const float* bq = (const float*)d_in[4];
  const float* Wk = (const float*)d_in[5];
  const float* bk = (const float*)d_in[6];
  const float* Wv = (const float*)d_in[7];
  const float* bv = (const float*)d_in[8];
  float* out = (float*)d_out;

  short* Qw = (short*)d_ws;  // [3][4096][1024] bf16 outputs (Q scaled 0.125*log2e)
  short* Kw = Qw + (size_t)4096 * 1024;
  short* Vw = Kw + (size_t)4096 * 1024;
  short* Xb = Vw + (size_t)4096 * 1024;      // [3][4096][1024] bf16 inputs
  short* Wb = Xb + (size_t)3 * 4096 * 1024;  // [3][1024][1024] bf16 weights

  const size_t need = ((size_t)6 * 4096 * 1024 + (size_t)3 * 1024 * 1024) * 2;

  if (ws_size >= need) {
    CvtArgs ca;
    ca.X[0] = query; ca.X[1] = key; ca.X[2] = value;
    ca.W[0] = Wq; ca.W[1] = Wk; ca.W[2] = Wv;
    ca.Xb = Xb; ca.Wb = Wb;
    cvt_kernel<<<7680, 256, 0, stream>>>(ca);

    Gemm2Args ga;
    ga.Xb = Xb; ga.Wb = Wb;
    ga.Bv[0] = bq; ga.Bv[1] = bk; ga.Bv[2] = bv;
    ga.Y[0] = Qw; ga.Y[1] = Kw; ga.Y[2] = Vw;
    ga.scale[0] = QSCALE; ga.scale[1] = 1.0f; ga.scale[2] = 1.0f;
    qkv_gemm_bf16<<<768, 256, 0, stream>>>(ga);
  } else {
    ProjArgs pa;
    pa.X[0] = query; pa.X[1] = key; pa.X[2] = value;
    pa.W[0] = Wq; pa.W[1] = Wk; pa.W[2] = Wv;
    pa.Bv[0] = bq; pa.Bv[1] = bk; pa.Bv[2] = bv;
    pa.Y[0] = Qw; pa.Y[1] = Kw; pa.Y[2] = Vw;
    pa.scale[0] = QSCALE; pa.scale[1] = 1.0f; pa.scale[2] = 1.0f;
    qkv_proj_fallback<<<dim3(1024 / PBN, 4096 / PBM, 3), 256, 0, stream>>>(pa);
  }

  attn_kernel<<<dim3(16, 2, 16), 512, 0, stream>>>(Qw, Kw, Vw, out);
}

// Round 9
// 104.916 us; speedup vs baseline: 1.9342x; 1.0936x over previous
//
#include <hip/hip_runtime.h>

// B=2, S=2048, H=1024, NH=16, HD=64
// Reference reshape [B,S,H]->[B,NH,S,HD] is a VIEW: head n = flat chunk
// [n*S*HD, (n+1)*S*HD) per batch, i.e. a [2048,64] row-major block.
// out[b,q,n*64+d] = softmax_k(Q_n[q,:]·K_n[k,:]/8) @ V_n[k,d]
// Q is pre-scaled by 0.125*log2(e) so softmax runs in exp2 domain.

typedef short s16x8 __attribute__((ext_vector_type(8)));
typedef float f32x4 __attribute__((ext_vector_type(4)));
typedef float f32x16 __attribute__((ext_vector_type(16)));
typedef unsigned int u32x2 __attribute__((ext_vector_type(2)));
typedef unsigned int u32x4 __attribute__((ext_vector_type(4)));
typedef float f32x4u __attribute__((ext_vector_type(4), aligned(4)));

#define MFMA16(a, b, c) __builtin_amdgcn_mfma_f32_16x16x32_bf16((a), (b), (c), 0, 0, 0)
#define MFMA32(a, b, c) __builtin_amdgcn_mfma_f32_32x32x16_bf16((a), (b), (c), 0, 0, 0)

__device__ __forceinline__ short f2bf(float f) {
  unsigned u = __builtin_bit_cast(unsigned, f);
  u = (u + 0x7fffu + ((u >> 16) & 1u)) >> 16;
  return (short)u;
}

__device__ __forceinline__ float exp2v(float x) {  // v_exp_f32 = 2^x
  float r;
  asm("v_exp_f32 %0, %1" : "=v"(r) : "v"(x));
  return r;
}

__device__ __forceinline__ float max3f(float a, float b, float c) {
  float r;
  asm("v_max3_f32 %0, %1, %2, %3" : "=v"(r) : "v"(a), "v"(b), "v"(c));
  return r;
}

#define QSCALE (0.125f * 1.44269504088896340736f)

// ================= Kernel 0: fp32 -> bf16 convert (X[3] then W[3]) =========
struct CvtArgs {
  const float* X[3];
  const float* W[3];
  short* Xb;  // [3][4096][1024]
  short* Wb;  // [3][1024][1024]
};

__global__ __launch_bounds__(256) void cvt_kernel(CvtArgs a) {
  const size_t t = (size_t)blockIdx.x * 256 + threadIdx.x;
  const size_t e = t * 8;
  const float* src;
  short* dst;
  size_t off;
  if (e < (size_t)3 * 4194304) {
    src = a.X[e >> 22];
    off = e & 4194303;
    dst = a.Xb + e;
  } else {
    const size_t e2 = e - (size_t)3 * 4194304;
    src = a.W[e2 >> 20];
    off = e2 & 1048575;
    dst = a.Wb + e2;
  }
  f32x4 v0 = *(const f32x4*)(src + off);
  f32x4 v1 = *(const f32x4*)(src + off + 4);
  s16x8 o;
#pragma unroll
  for (int j = 0; j < 4; ++j) { o[j] = f2bf(v0[j]); o[j + 4] = f2bf(v1[j]); }
  *(s16x8*)dst = o;
}

// ================= Kernel 1b: bf16 GEMM (unchanged from R8) ================
struct Gemm2Args {
  const short* Xb;
  const short* Wb;
  const float* Bv[3];
  short* Y[3];
  float scale[3];
};

__global__ __launch_bounds__(256) void qkv_gemm_bf16(Gemm2Args a) {
  const int L = (blockIdx.x & 7) * 96 + (blockIdx.x >> 3);
  const int n_t = L & 7;
  const int m_t = (L >> 3) & 31;
  const int z = L >> 8;

  const short* __restrict__ Xz = a.Xb + (size_t)z * 4096 * 1024;
  const short* __restrict__ Wz = a.Wb + (size_t)z * 1024 * 1024;
  const float* __restrict__ Bv = a.Bv[z];
  short* __restrict__ Y = a.Y[z];
  const float scale = a.scale[z];

  __shared__ __align__(16) short Smem[2][2][8192];

  const int tid = threadIdx.x;
  const int lane = tid & 63;
  const int wave = tid >> 6;
  const int m0 = m_t * 128;
  const int n0 = n_t * 128;
  const int moff = (wave >> 1) * 64;
  const int noff = (wave & 1) * 64;
  const int fr = lane & 15;
  const int fk = (lane >> 4) * 8;
  const int fsw = (fr & 7) * 8;

  const int srow = lane >> 3;
  const int scolX = ((lane & 7) ^ (lane >> 3)) * 8;

  f32x4 acc[4][4] = {};

  auto stage = [&](int buf, int k0) {
#pragma unroll
    for (int i = 0; i < 4; ++i) {
      const int c = wave * 4 + i;
      const short* ga = Xz + (size_t)(m0 + c * 8 + srow) * 1024 + k0 + scolX;
      const short* gb = Wz + (size_t)(n0 + c * 8 + srow) * 1024 + k0 + scolX;
      __builtin_amdgcn_global_load_lds(
          (const __attribute__((address_space(1))) unsigned int*)ga,
          (__attribute__((address_space(3))) unsigned int*)&Smem[buf][0][c * 512], 16, 0, 0);
      __builtin_amdgcn_global_load_lds(
          (const __attribute__((address_space(1))) unsigned int*)gb,
          (__attribute__((address_space(3))) unsigned int*)&Smem[buf][1][c * 512], 16, 0, 0);
    }
  };

  stage(0, 0);
  for (int t = 0; t < 16; ++t) {
    const int buf = t & 1;
    if (t < 15) {
      stage(buf ^ 1, (t + 1) * 64);
      asm volatile("s_waitcnt vmcnt(8)" ::: "memory");
    } else {
      asm volatile("s_waitcnt vmcnt(0)" ::: "memory");
    }
    __builtin_amdgcn_s_barrier();
    __builtin_amdgcn_sched_barrier(0);

    const short* Asb = &Smem[buf][0][0];
    const short* Bsb = &Smem[buf][1][0];
#pragma unroll
    for (int kk = 0; kk < 64; kk += 32) {
      s16x8 af[4], bf[4];
#pragma unroll
      for (int i = 0; i < 4; ++i)
        af[i] = *(const s16x8*)&Asb[(moff + i * 16 + fr) * 64 + ((kk + fk) ^ fsw)];
#pragma unroll
      for (int j = 0; j < 4; ++j)
        bf[j] = *(const s16x8*)&Bsb[(noff + j * 16 + fr) * 64 + ((kk + fk) ^ fsw)];
#pragma unroll
      for (int i = 0; i < 4; ++i)
#pragma unroll
        for (int j = 0; j < 4; ++j)
          acc[i][j] = MFMA16(af[i], bf[j], acc[i][j]);
    }
    __builtin_amdgcn_s_barrier();
    __builtin_amdgcn_sched_barrier(0);
  }

  short* Cs = &Smem[0][0][0];  // [128][136] shorts
  const int l16 = lane >> 4;
#pragma unroll
  for (int j = 0; j < 4; ++j) {
    const int col = noff + j * 16 + fr;
    const float bias = Bv[n0 + col];
#pragma unroll
    for (int i = 0; i < 4; ++i) {
      const int rowb = moff + i * 16 + l16 * 4;
#pragma unroll
      for (int r = 0; r < 4; ++r)
        Cs[(rowb + r) * 136 + col] = f2bf((acc[i][j][r] + bias) * scale);
    }
  }
  __syncthreads();
  {
    const int row = tid >> 1;
    const int c0 = (tid & 1) * 64;
    short* dst = Y + (size_t)(m0 + row) * 1024 + n0 + c0;
    const short* src = &Cs[row * 136 + c0];
#pragma unroll
    for (int p = 0; p < 8; ++p)
      *(s16x8*)(dst + p * 8) = *(const s16x8*)(src + p * 8);
  }
}

// ================= Kernel 1 (fallback, fp32 inputs) ========================
struct ProjArgs {
  const float* X[3];
  const float* W[3];
  const float* Bv[3];
  short* Y[3];
  float scale[3];
};

#define PBM 128
#define PBN 128
#define PBK 32
#define PLD (PBK + 8)

__global__ __launch_bounds__(256) void qkv_proj_fallback(ProjArgs args) {
  const int z = blockIdx.z;
  const float* __restrict__ X = args.X[z];
  const float* __restrict__ W = args.W[z];
  const float* __restrict__ Bv = args.Bv[z];
  short* __restrict__ Y = args.Y[z];
  const float scale = args.scale[z];

  __shared__ __align__(16) short As[PBM][PLD];
  __shared__ __align__(16) short Bs[PBN][PLD];

  const int tid = threadIdx.x;
  const int lane = tid & 63;
  const int wave = tid >> 6;
  const int m0 = blockIdx.y * PBM;
  const int n0 = blockIdx.x * PBN;
  const int moff = (wave >> 1) * 64;
  const int noff = (wave & 1) * 64;
  const int fr = lane & 15;
  const int fk = (lane >> 4) * 8;

  const int srow = tid >> 1;
  const int scol = (tid & 1) * 16;

  f32x4 acc[4][4] = {};

  const float* ap = X + (size_t)(m0 + srow) * 1024 + scol;
  const float* bp = W + (size_t)(n0 + srow) * 1024 + scol;

  for (int k0 = 0; k0 < 1024; k0 += PBK) {
    f32x4 a0 = *(const f32x4*)(ap + k0);
    f32x4 a1 = *(const f32x4*)(ap + k0 + 4);
    f32x4 a2 = *(const f32x4*)(ap + k0 + 8);
    f32x4 a3 = *(const f32x4*)(ap + k0 + 12);
    f32x4 b0 = *(const f32x4*)(bp + k0);
    f32x4 b1 = *(const f32x4*)(bp + k0 + 4);
    f32x4 b2 = *(const f32x4*)(bp + k0 + 8);
    f32x4 b3 = *(const f32x4*)(bp + k0 + 12);

    s16x8 sa0, sa1, sb0, sb1;
#pragma unroll
    for (int j = 0; j < 4; ++j) {
      sa0[j] = f2bf(a0[j]); sa0[j + 4] = f2bf(a1[j]);
      sa1[j] = f2bf(a2[j]); sa1[j + 4] = f2bf(a3[j]);
      sb0[j] = f2bf(b0[j]); sb0[j + 4] = f2bf(b1[j]);
      sb1[j] = f2bf(b2[j]); sb1[j + 4] = f2bf(b3[j]);
    }

    __syncthreads();
    *(s16x8*)&As[srow][scol]     = sa0;
    *(s16x8*)&As[srow][scol + 8] = sa1;
    *(s16x8*)&Bs[srow][scol]     = sb0;
    *(s16x8*)&Bs[srow][scol + 8] = sb1;
    __syncthreads();

    s16x8 af[4], bfm[4];
#pragma unroll
    for (int i = 0; i < 4; ++i) af[i] = *(const s16x8*)&As[moff + i * 16 + fr][fk];
#pragma unroll
    for (int j = 0; j < 4; ++j) bfm[j] = *(const s16x8*)&Bs[noff + j * 16 + fr][fk];
#pragma unroll
    for (int i = 0; i < 4; ++i)
#pragma unroll
      for (int j = 0; j < 4; ++j)
        acc[i][j] = MFMA16(af[i], bfm[j], acc[i][j]);
  }

#pragma unroll
  for (int j = 0; j < 4; ++j) {
    const int col = n0 + noff + j * 16 + fr;
    const float bias = Bv[col];
#pragma unroll
    for (int i = 0; i < 4; ++i) {
      const int rowb = m0 + moff + i * 16 + (lane >> 4) * 4;
#pragma unroll
      for (int r = 0; r < 4; ++r) {
        Y[(size_t)(rowb + r) * 1024 + col] = f2bf((acc[i][j][r] + bias) * scale);
      }
    }
  }
}

// ================= Kernel 2: flash attention, KVB=128, gload_lds staging ===
// 256 thr (4 waves), wave owns 32 q-rows. Per iter: stage next 128-row K/V
// tile via global_load_lds (source-swizzled, rule #21), QK (16 MFMA32),
// single softmax over 128 k, PV in two 64-k halves via tr_b16.
#define TRR(dst, base, OFF) \
  asm volatile("ds_read_b64_tr_b16 %0, %1 offset:" OFF : "=v"(dst) : "v"(base))

__global__ __launch_bounds__(256, 2) void attn_kernel(
    const short* __restrict__ Qb, const short* __restrict__ Kb,
    const short* __restrict__ Vb, float* __restrict__ out) {
  const int head = blockIdx.x;  // 0..15
  const int bz = blockIdx.y;    // 0..1
  const int qb = blockIdx.z;    // 0..15

  const size_t hb = (size_t)bz * (2048 * 1024) + (size_t)head * (2048 * 64);
  const short* __restrict__ Qh = Qb + hb;
  const short* __restrict__ Kh = Kb + hb;
  const short* __restrict__ Vh = Vb + hb;

  // K: [128 rows][128B], content XOR-swizzled via pre-swizzled SOURCE col.
  // V: subtiled [k>>2][d>>4][k&3][d&15], written linearly by gload_lds with
  //    inverse-mapped per-lane source addresses.
  __shared__ __align__(16) short Klds[2][8192];
  __shared__ __align__(16) short Vlds[2][8192];

  const int tid = threadIdx.x;
  const int lane = tid & 63;
  const int wave = tid >> 6;
  const int l31 = lane & 31;
  const int hi = lane >> 5;

  const int q0w = qb * 128 + wave * 32;
  s16x8 qf[4];
#pragma unroll
  for (int f = 0; f < 4; ++f)
    qf[f] = *(const s16x8*)(Qh + (size_t)(q0w + l31) * 64 + f * 16 + hi * 8);

  // per-lane SOURCE offsets (shorts) for gload_lds staging of one 1KB chunk:
  // K: lds(row=c8+(l>>3), colblk=(l&7)) holds K[row][(l&7)^(row&7) blk]
  const int ksrcl = (lane >> 3) * 64 + (((lane & 7) ^ (lane >> 3)) * 8);
  // V: lds linear lane slot -> subtile s=c8+(l>>3), off=(l&7)*8 ->
  //    k = c*8 + (l>>5)*4 + ((l&7)>>1), d = ((l>>3)&3)*16 + (l&1)*8
  const int vsrcl = ((lane >> 5) * 4 + ((lane & 7) >> 1)) * 64 +
                    ((lane >> 3) & 3) * 16 + (lane & 1) * 8;

  int cXor[4];
#pragma unroll
  for (int f = 0; f < 4; ++f) cXor[f] = ((f * 32 + hi * 16) ^ ((l31 & 7) << 4));

  const unsigned vlane = (unsigned)(hi * 1024 + ((l31 >> 4) * 128) + (lane & 15) * 8);

  auto stage = [&](int buf, int tile) {
#pragma unroll
    for (int i = 0; i < 4; ++i) {
      const int c = wave * 4 + i;
      const short* ks = Kh + (size_t)tile * 8192 + c * 512 + ksrcl;
      const short* vs = Vh + (size_t)tile * 8192 + c * 512 + vsrcl;
      __builtin_amdgcn_global_load_lds(
          (const __attribute__((address_space(1))) unsigned int*)ks,
          (__attribute__((address_space(3))) unsigned int*)&Klds[buf][c * 512], 16, 0, 0);
      __builtin_amdgcn_global_load_lds(
          (const __attribute__((address_space(1))) unsigned int*)vs,
          (__attribute__((address_space(3))) unsigned int*)&Vlds[buf][c * 512], 16, 0, 0);
    }
  };

  stage(0, 0);

  float m = -1e30f, lsum = 0.f;
  f32x16 acc0 = {}, acc1 = {};

  for (int t = 0; t < 16; ++t) {
    __syncthreads();  // drains last iter's gload_lds (full compute phase ago)
    const int cur = t & 1;
    if (t < 15) stage(cur ^ 1, t + 1);

    // ---- QK: E^T[k][q] for 128 k-rows
    const char* kl = (const char*)&Klds[cur][0];
    f32x16 et[4] = {};
    __builtin_amdgcn_s_setprio(1);
#pragma unroll
    for (int X = 0; X < 4; ++X)
#pragma unroll
      for (int f = 0; f < 4; ++f) {
        s16x8 kf = *(const s16x8*)(kl + X * 4096 + l31 * 128 + cXor[f]);
        et[X] = MFMA32(kf, qf[f], et[X]);
      }
    __builtin_amdgcn_s_setprio(0);

    // ---- issue PV half-A tr reads early (hidden under softmax)
    const unsigned vb = (unsigned)(size_t)((const char*)&Vlds[cur][0]) + vlane;
    u32x2 vaA[2][4][2];
    TRR(vaA[0][0][0], vb, "0");    TRR(vaA[0][0][1], vb, "512");
    TRR(vaA[0][1][0], vb, "2048"); TRR(vaA[0][1][1], vb, "2560");
    TRR(vaA[0][2][0], vb, "4096"); TRR(vaA[0][2][1], vb, "4608");
    TRR(vaA[0][3][0], vb, "6144"); TRR(vaA[0][3][1], vb, "6656");
    TRR(vaA[1][0][0], vb, "256");  TRR(vaA[1][0][1], vb, "768");
    TRR(vaA[1][1][0], vb, "2304"); TRR(vaA[1][1][1], vb, "2816");
    TRR(vaA[1][2][0], vb, "4352"); TRR(vaA[1][2][1], vb, "4864");
    TRR(vaA[1][3][0], vb, "6400"); TRR(vaA[1][3][1], vb, "6912");

    // ---- softmax over 128 k (exp2 domain, defer-max THR=8)
    float mx[16];
#pragma unroll
    for (int r = 0; r < 16; ++r)
      mx[r] = max3f(et[0][r], et[1][r], fmaxf(et[2][r], et[3][r]));
    const float u0 = max3f(mx[0], mx[1], mx[2]);
    const float u1 = max3f(mx[3], mx[4], mx[5]);
    const float u2 = max3f(mx[6], mx[7], mx[8]);
    const float u3 = max3f(mx[9], mx[10], mx[11]);
    const float u4 = max3f(mx[12], mx[13], mx[14]);
    const float u5 = max3f(u0, u1, mx[15]);
    const float u6 = max3f(u2, u3, u4);
    const float tmax = fmaxf(u5, u6);
    if (__any(tmax > m + 8.f)) {
      const float mt = fmaxf(tmax, __shfl_xor(tmax, 32));
      const float mnew = fmaxf(m, mt);
      const float corr = exp2v(m - mnew);
      lsum *= corr;
      acc0 *= corr;
      acc1 *= corr;
      m = mnew;
    }

    float sacc[16];
    s16x8 pfA[4], pfB[4];
#pragma unroll
    for (int T = 0; T < 4; ++T) {
      float pv[16];
#pragma unroll
      for (int r = 0; r < 16; ++r) {
        pv[r] = exp2v(et[T][r] - m);
        if (T == 0) sacc[r] = pv[r]; else sacc[r] += pv[r];
      }
      unsigned xr[4], yr[4];
#pragma unroll
      for (int c = 0; c < 4; ++c) {
        asm("v_cvt_pk_bf16_f32 %0, %1, %2" : "=v"(xr[c]) : "v"(pv[4 * c + 0]), "v"(pv[4 * c + 1]));
        asm("v_cvt_pk_bf16_f32 %0, %1, %2" : "=v"(yr[c]) : "v"(pv[4 * c + 2]), "v"(pv[4 * c + 3]));
      }
#pragma unroll
      for (int u = 0; u < 2; ++u) {
        unsigned w0 = xr[2 * u], w2 = xr[2 * u + 1];
        unsigned w1 = yr[2 * u], w3 = yr[2 * u + 1];
        asm("v_permlane32_swap_b32 %0, %1" : "+v"(w0), "+v"(w2));
        asm("v_permlane32_swap_b32 %0, %1" : "+v"(w1), "+v"(w3));
        u32x4 w = {w0, w1, w2, w3};
        if (T < 2) pfA[2 * T + u] = __builtin_bit_cast(s16x8, w);
        else       pfB[2 * (T - 2) + u] = __builtin_bit_cast(s16x8, w);
      }
    }
#pragma unroll
    for (int s2 = 8; s2 >= 1; s2 >>= 1)
#pragma unroll
      for (int r = 0; r < 8; ++r)
        if (r < s2) sacc[r] += sacc[r + s2];
    lsum += sacc[0] + __shfl_xor(sacc[0], 32);

    // ---- PV half A (k 0..63); issue half-B reads to hide under MFMAs
    asm volatile("s_waitcnt lgkmcnt(0)" ::: "memory");
    __builtin_amdgcn_sched_barrier(0);
    u32x2 vaB[2][4][2];
    TRR(vaB[0][0][0], vb, "8192");  TRR(vaB[0][0][1], vb, "8704");
    TRR(vaB[0][1][0], vb, "10240"); TRR(vaB[0][1][1], vb, "10752");
    TRR(vaB[0][2][0], vb, "12288"); TRR(vaB[0][2][1], vb, "12800");
    TRR(vaB[0][3][0], vb, "14336"); TRR(vaB[0][3][1], vb, "14848");
    TRR(vaB[1][0][0], vb, "8448");  TRR(vaB[1][0][1], vb, "8960");
    TRR(vaB[1][1][0], vb, "10496"); TRR(vaB[1][1][1], vb, "11008");
    TRR(vaB[1][2][0], vb, "12544"); TRR(vaB[1][2][1], vb, "13056");
    TRR(vaB[1][3][0], vb, "14592"); TRR(vaB[1][3][1], vb, "15104");
    __builtin_amdgcn_s_setprio(1);
#pragma unroll
    for (int k0i = 0; k0i < 4; ++k0i) {
      u32x4 w0 = {vaA[0][k0i][0][0], vaA[0][k0i][0][1], vaA[0][k0i][1][0], vaA[0][k0i][1][1]};
      u32x4 w1 = {vaA[1][k0i][0][0], vaA[1][k0i][0][1], vaA[1][k0i][1][0], vaA[1][k0i][1][1]};
      acc0 = MFMA32(__builtin_bit_cast(s16x8, w0), pfA[k0i], acc0);
      acc1 = MFMA32(__builtin_bit_cast(s16x8, w1), pfA[k0i], acc1);
    }
    __builtin_amdgcn_s_setprio(0);

    // ---- PV half B (k 64..127)
    asm volatile("s_waitcnt lgkmcnt(0)" ::: "memory");
    __builtin_amdgcn_sched_barrier(0);
    __builtin_amdgcn_s_setprio(1);
#pragma unroll
    for (int k0i = 0; k0i < 4; ++k0i) {
      u32x4 w0 = {vaB[0][k0i][0][0], vaB[0][k0i][0][1], vaB[0][k0i][1][0], vaB[0][k0i][1][1]};
      u32x4 w1 = {vaB[1][k0i][0][0], vaB[1][k0i][0][1], vaB[1][k0i][1][0], vaB[1][k0i][1][1]};
      acc0 = MFMA32(__builtin_bit_cast(s16x8, w0), pfB[k0i], acc0);
      acc1 = MFMA32(__builtin_bit_cast(s16x8, w1), pfB[k0i], acc1);
    }
    __builtin_amdgcn_s_setprio(0);
  }

  // ---- epilogue: O^T col q = lane&31, row d = (r&3)+8*(r>>2)+4*hi (+32 acc1)
  const float inv = 1.0f / lsum;
  acc0 *= inv;
  acc1 *= inv;
  float* op = out + ((size_t)bz * 2048 + q0w + l31) * 1024 + head * 64;
#pragma unroll
  for (int c = 0; c < 4; ++c) {
    f32x4u v0 = {acc0[4 * c + 0], acc0[4 * c + 1], acc0[4 * c + 2], acc0[4 * c + 3]};
    f32x4u v1 = {acc1[4 * c + 0], acc1[4 * c + 1], acc1[4 * c + 2], acc1[4 * c + 3]};
    *(f32x4u*)(op + 8 * c + 4 * hi) = v0;
    *(f32x4u*)(op + 32 + 8 * c + 4 * hi) = v1;
  }
}

extern "C" void kernel_launch(void* const* d_in, const int* in_sizes, int n_in,
                              void* d_out, int out_size, void* d_ws, size_t ws_size,
                              hipStream_t stream) {
  const float* query = (const float*)d_in[0];
  const float* key   = (const float*)d_in[1];
  const float* value = (const float*)d_in[2];
  const float* Wq = (const float*)d_in[3];
  const float* bq = (const float*)d_in[4];
  const float* Wk = (const float*)d_in[5];
  const float* bk = (const float*)d_in[6];
  const float* Wv = (const float*)d_in[7];
  const float* bv = (const float*)d_in[8];
  float* out = (float*)d_out;

  short* Qw = (short*)d_ws;  // [3][4096][1024] bf16 outputs (Q scaled 0.125*log2e)
  short* Kw = Qw + (size_t)4096 * 1024;
  short* Vw = Kw + (size_t)4096 * 1024;
  short* Xb = Vw + (size_t)4096 * 1024;      // [3][4096][1024] bf16 inputs
  short* Wb = Xb + (size_t)3 * 4096 * 1024;  // [3][1024][1024] bf16 weights

  const size_t need = ((size_t)6 * 4096 * 1024 + (size_t)3 * 1024 * 1024) * 2;

  if (ws_size >= need) {
    CvtArgs ca;
    ca.X[0] = query; ca.X[1] = key; ca.X[2] = value;
    ca.W[0] = Wq; ca.W[1] = Wk; ca.W[2] = Wv;
    ca.Xb = Xb; ca.Wb = Wb;
    cvt_kernel<<<7680, 256, 0, stream>>>(ca);

    Gemm2Args ga;
    ga.Xb = Xb; ga.Wb = Wb;
    ga.Bv[0] = bq; ga.Bv[1] = bk; ga.Bv[2] = bv;
    ga.Y[0] = Qw; ga.Y[1] = Kw; ga.Y[2] = Vw;
    ga.scale[0] = QSCALE; ga.scale[1] = 1.0f; ga.scale[2] = 1.0f;
    qkv_gemm_bf16<<<768, 256, 0, stream>>>(ga);
  } else {
    ProjArgs pa;
    pa.X[0] = query; pa.X[1] = key; pa.X[2] = value;
    pa.W[0] = Wq; pa.W[1] = Wk; pa.W[2] = Wv;
    pa.Bv[0] = bq; pa.Bv[1] = bk; pa.Bv[2] = bv;
    pa.Y[0] = Qw; pa.Y[1] = Kw; pa.Y[2] = Vw;
    pa.scale[0] = QSCALE; pa.scale[1] = 1.0f; pa.scale[2] = 1.0f;
    qkv_proj_fallback<<<dim3(1024 / PBN, 4096 / PBM, 3), 256, 0, stream>>>(pa);
  }

  attn_kernel<<<dim3(16, 2, 16), 256, 0, stream>>>(Qw, Kw, Vw, out);
}